// Round 7
// baseline (16443.170 us; speedup 1.0000x reference)
//
#include <hip/hip_runtime.h>
#include <stdint.h>

// ---------------------------------------------------------------------------
// AnmNetwork: ADMM-like complex PSD iteration. B=64, m=l=64, n=128, K=10.
//  * Sita = V relu(w + minv[rank]) V^H  (second eigh mathematically redundant)
//  * Lamda_new = (1 - eta/rho) Lamda + eta * V diag(relu(w+m)-w) V^H
//  * Output depends only on state entering iteration K-1 -> 9 eigh rounds.
//  * PRNG: JAX threefry2x32 partitionable counters (bit-exact, R5).
// R19 = R18 (1-barrier round, RSA=130, param pipelining) + WAVE0 DEBLOAT
// (R18 post-mortem: wave0 = 3 rots + pcalc was the per-round straggler;
// 15 waves wait on it at the barrier):
//  * pcalc(r+1) inputs re-derived: d0 diag cells + d2 cross cells ONLY,
//    plus two edge cells in blocks (0,1) and (62,63) (lanes 0/63, both
//    sweep directions). d=1 blocks otherwise NOT pcalc inputs.
//  * Wave0 keeps d0 (64) + d2 (62) + edge-d1 (0,1),(62,63) = 128 blocks
//    = exactly 2 rots/lane + pcalc. 61 d1 blocks move to the rest pool
//    (1952 blocks over threads 64..1023; 32 threads take a 3rd).
//  * Diag (d0) rot specialized: B10 = conj(B01) (same cell, 1 read saved);
//    the (p,q) store on the 01-path was always overwritten by the 10-path
//    store -> dropped (1 write saved). Last-write value identical ->
//    bit-exact.
// State (Theta/Lamda), PRNG, u, writeout stay fp64. SWEEPS=7.
// ---------------------------------------------------------------------------

#define BATCH 64
#define MDIM 64
#define LDIM 64
#define NDIM 128
#define NSQ (NDIM * NDIM)
#define KITER 10
#define SWEEPS 7
#define RSA 130                                 // A row stride (float2 units)
#define JAC_LDS_BYTES (NDIM * RSA * (int)sizeof(float2))   // 133,120 B
#define RCH 12                                  // replay chunk col stride (dwords, 48B)
#define OUT_ELEMS 266240   // 64*64*64 (T) + 64*64 (uvec), f32 real parts

// ----------------------------- threefry2x32 --------------------------------
__device__ __forceinline__ void tf_block(unsigned k0, unsigned k1,
                                         unsigned& x0, unsigned& x1) {
  unsigned k2 = k0 ^ k1 ^ 0x1BD11BDAu;
  x0 += k0; x1 += k1;
#define TF_R(r) { x0 += x1; x1 = (x1 << (r)) | (x1 >> (32 - (r))); x1 ^= x0; }
  TF_R(13) TF_R(15) TF_R(26) TF_R(6)
  x0 += k1; x1 += k2 + 1u;
  TF_R(17) TF_R(29) TF_R(16) TF_R(24)
  x0 += k2; x1 += k0 + 2u;
  TF_R(13) TF_R(15) TF_R(26) TF_R(6)
  x0 += k0; x1 += k1 + 3u;
  TF_R(17) TF_R(29) TF_R(16) TF_R(24)
  x0 += k1; x1 += k2 + 4u;
  TF_R(13) TF_R(15) TF_R(26) TF_R(6)
  x0 += k2; x1 += k0 + 5u;
#undef TF_R
}

// ------------------------------- erfinv (f64) ------------------------------
__device__ double erfinv_d(double x) {
  double w = -log1p(-x * x);
  double p;
  if (w < 6.25) {
    w -= 3.125;
    const double c[23] = {
      -3.6444120640178196996e-21, -1.685059138182016589e-19,
      1.2858480715256400167e-18,  1.115787767802518096e-17,
      -1.333171662854620906e-16,  2.0972767875968561637e-17,
      6.6376381343583238325e-15,  -4.0545662729752068639e-14,
      -8.1519341976054721522e-14, 2.6335093153082322977e-12,
      -1.2975133253453532498e-11, -5.4154120542946279317e-11,
      1.051212273321532285e-09,   -4.1126339803469836976e-09,
      -2.9070369957882005086e-08, 4.2347877827932403518e-07,
      -1.3654692000834678645e-06, -1.3882523362786468719e-05,
      1.8673420803405714802e-04,  -7.4070253416626697512e-04,
      -6.0336708714301490533e-03, 2.4015818242558961693e-01,
      1.6536545626831027356e+00};
    p = c[0];
#pragma unroll
    for (int i = 1; i < 23; ++i) p = p * w + c[i];
  } else if (w < 16.0) {
    double s = sqrt(w) - 3.25;
    const double c[19] = {
      2.2137376921775787049e-09,  9.0756561938885390979e-08,
      -2.7517406297064545428e-07, 1.8239629214389227755e-08,
      1.5027403968909827627e-06,  -4.013867526981545969e-06,
      2.9234449089955446044e-06,  1.2475304481671778723e-05,
      -4.7318229009055733981e-05, 6.8284851459573175448e-05,
      2.4031110387097893999e-05,  -3.5503752036284748449e-04,
      9.5328937973738049703e-04,  -1.6882755560235047313e-03,
      2.4914420961078508066e-03,  -3.7512085075692412107e-03,
      5.3709145535900636051e-03,  1.0052589676941592334e+00,
      3.0838856104922207635e+00};
    p = c[0];
#pragma unroll
    for (int i = 1; i < 19; ++i) p = p * s + c[i];
  } else {
    double s = sqrt(w) - 5.0;
    const double c[17] = {
      -2.7109920616438573243e-11, -2.5556418169965252055e-10,
      1.5076572693500548083e-09,  -3.7894654401267369937e-09,
      7.6157012080783393804e-09,  -1.4960026627149240478e-08,
      2.9147953450901080826e-08,  -6.7711997758452339498e-08,
      2.2900482228026654717e-07,  -9.9298272942317002539e-07,
      4.5260625972231537039e-06,  -1.9681778105531670567e-05,
      7.5995277030017761139e-05,  -2.1503011930044477347e-04,
      -1.3871931833623122026e-04, 1.0103004648645343977e+00,
      4.8499064014085844221e+00};
    p = c[0];
#pragma unroll
    for (int i = 1; i < 17; ++i) p = p * s + c[i];
  }
  double z = p * x;
  const double spi2 = 0.8862269254527580;  // sqrt(pi)/2
  double ax = fabs(x);
#pragma unroll
  for (int nr = 0; nr < 2; ++nr) {
    if (ax > 0.9375) {
      double az = fabs(z);
      double corr = (erfc(az) - (1.0 - ax)) * spi2 * exp(az * az);
      az += corr;
      z = copysign(az, x);
    } else {
      z -= (erf(z) - x) * spi2 * exp(z * z);
    }
  }
  return z;
}

// ------------------------------- kernels -----------------------------------
__global__ void zero_kernel(double* p, size_t n) {
  size_t i = (size_t)blockIdx.x * blockDim.x + threadIdx.x;
  size_t stride = (size_t)gridDim.x * blockDim.x;
  for (; i < n; i += stride) p[i] = 0.0;
}

__global__ void flags_zero_kernel(unsigned* flags) {
  int tid = threadIdx.x;
  if (tid < BATCH * SWEEPS) flags[tid] = 0u;
}

__global__ void prng_kernel(double* minv) {
  int tid = blockIdx.x * blockDim.x + threadIdx.x;
  if (tid >= KITER * BATCH * NDIM) return;
  int it = tid / (BATCH * NDIM);
  int i = tid % (BATCH * NDIM);
  unsigned nk0 = 0u, nk1 = (unsigned)it;
  tf_block(0u, 42u, nk0, nk1);                       // fold_in
  unsigned c0 = 0u, c1 = (unsigned)i;                // partitionable counter
  tf_block(nk0, nk1, c0, c1);
  unsigned long long bits = ((unsigned long long)c0 << 32) | (unsigned long long)c1;
  unsigned long long fb = (bits >> 12) | 0x3FF0000000000000ull;
  double f = __builtin_bit_cast(double, fb) - 1.0;
  const double lo = __builtin_bit_cast(double, 0xBFEFFFFFFFFFFFFFull);
  double uu = f * 2.0 + lo;
  if (uu < lo) uu = lo;
  minv[tid] = 1.4142135623730951 * erfinv_d(uu);
}

__global__ void compute_u_kernel(const double2* Theta, const double2* Lamda,
                                 const float* rho, const float* tau, int it,
                                 double2* u) {
  int tid = blockIdx.x * blockDim.x + threadIdx.x;
  if (tid >= BATCH * MDIM) return;
  int b = tid / MDIM, kk = tid % MDIM;
  double r = (double)rho[it], t = (double)tau[it];
  const double2* Lb = Lamda + (size_t)b * NSQ;
  const double2* Tb = Theta + (size_t)b * NSQ;
  double ar = 0.0, ai = 0.0;
  for (int i = 0; i + kk < MDIM; ++i) {
    double2 L = Lb[i * NDIM + i + kk];
    double2 Th = Tb[i * NDIM + i + kk];
    ar += L.x + r * Th.x;
    ai += L.y + r * Th.y;
  }
  if (kk == 0) ar += -(t * 0.5) * (double)MDIM;
  double s = 1.0 / ((double)(MDIM - kk) * r);
  u[b * MDIM + kk] = make_double2(ar * s, ai * s);
}

// A32 = fp32(StackM - Lamda/r)   (U init lives in combined_all: U = I)
__global__ void assemble_kernel(const double2* Theta, const double2* Lamda,
                                const double2* u, const float* Yre, const float* Yim,
                                const float* rho, const float* tau, int it,
                                float2* A32) {
  int tid = blockIdx.x * 256 + threadIdx.x;
  if (tid >= BATCH * NSQ) return;
  int b = tid / NSQ, rem = tid % NSQ, i = rem / NDIM, j = rem % NDIM;
  double r = (double)rho[it], t = (double)tau[it];
  size_t idx = (size_t)b * NSQ + rem;
  double2 L = Lamda[idx], Th = Theta[idx];
  double axr, axi;
  if (i < MDIM && j < MDIM) {
    int d = j - i;
    double2 uv = u[b * MDIM + (d >= 0 ? d : -d)];
    double uy = (d >= 0) ? uv.y : -uv.y;
    axr = uv.x - L.x / r;
    axi = uy - L.y / r;
  } else if (i < MDIM) {
    double yr = (double)Yre[(b * MDIM + i) * LDIM + (j - MDIM)];
    double yi = (double)Yim[(b * MDIM + i) * LDIM + (j - MDIM)];
    double inv = 1.0 / (1.0 + 2.0 * r);
    axr = (yr + 2.0 * L.x + 2.0 * r * Th.x) * inv - L.x / r;
    axi = (yi + 2.0 * L.y + 2.0 * r * Th.y) * inv - L.y / r;
  } else if (j < MDIM) {
    double yr = (double)Yre[(b * MDIM + j) * LDIM + (i - MDIM)];
    double yi = -(double)Yim[(b * MDIM + j) * LDIM + (i - MDIM)];
    double inv = 1.0 / (1.0 + 2.0 * r);
    axr = (yr + 2.0 * L.x + 2.0 * r * Th.x) * inv - L.x / r;
    axi = (yi + 2.0 * L.y + 2.0 * r * Th.y) * inv - L.y / r;
  } else {
    axr = Th.x - ((i == j) ? t / (2.0 * r) : 0.0);
    axi = Th.y;
  }
  A32[idx] = make_float2((float)axr, (float)axi);
}

__device__ __forceinline__ int pair_p(int j, int r) {
  return (j == 0) ? 0 : 1 + (j - 1 + r) % 127;
}
__device__ __forceinline__ int pair_q(int j, int r) {
  return 1 + (126 - j + r) % 127;
}

// Canonical-upper accessors (AoS float2 plane, stride RSA) -> single b64 op.
__device__ __forceinline__ float2 ldc2(const float2* sA, int r, int c) {
  int rr = r <= c ? r : c, cc = r <= c ? c : r;
  float2 v = sA[rr * RSA + cc];
  if (r > c) v.y = -v.y;
  return v;
}
__device__ __forceinline__ void stc2(float2* sA, int r, int c, float zr, float zi) {
  int rr = r <= c ? r : c, cc = r <= c ? c : r;
  sA[rr * RSA + cc] = make_float2(zr, (r <= c) ? zi : -zi);
}

// Raw barrier: drain own LDS ops only -- wave0's Pg global stores stay in
// flight (drained once per sweep by the RELEASE atomic on the same wave).
__device__ __forceinline__ void bar_lgkm() {
  asm volatile("s_waitcnt lgkmcnt(0)" ::: "memory");
  __builtin_amdgcn_s_barrier();
}

// Fused dispatch: blocks 0..63 jacobi (all 7 sweeps, A LDS-resident, params
// released per sweep via device-scope flags); blocks 64..191 replay (U chunk
// LDS-resident across all 7 sweeps, init to I, acquire-spin per sweep).
__global__ __launch_bounds__(1024) void combined_all_kernel(
    const float2* __restrict__ A, float2* __restrict__ U,
    float2* __restrict__ prm,        // [SWEEPS][BATCH][127][64]
    unsigned* __restrict__ flags,    // [BATCH][SWEEPS]
    const double* __restrict__ minv, int it,
    double* __restrict__ d1, double* __restrict__ d2) {
  extern __shared__ float smem[];
  int tid = threadIdx.x;

  if (blockIdx.x >= BATCH) {
    // ------------------------- replay path --------------------------------
    if (tid >= 512) return;   // 8 working waves; no block barriers here
    int rb = blockIdx.x - BATCH;
    int wv = tid >> 6, ln = tid & 63;
    int b = rb >> 1, half = rb & 1;
    int col0 = (half * 8 + wv) * 8;
    float* cre = smem + wv * (2 * NDIM * RCH);
    float* cim = cre + NDIM * RCH;
    // U = I (chunk init in LDS; no global load)
    for (int e = ln; e < NDIM * 8; e += 64) {
      int row = e >> 3, c = e & 7;
      cre[row * RCH + c] = (row == col0 + c) ? 1.0f : 0.0f;
      cim[row * RCH + c] = 0.0f;
    }
    for (int s = 0; s < SWEEPS; ++s) {
      const float2* Pg = prm + ((size_t)s * BATCH + b) * (127 * 64);
      if (ln == 0) {   // per-wave acquire spin (waves are independent)
        while (__hip_atomic_load(&flags[b * SWEEPS + s], __ATOMIC_ACQUIRE,
                                 __HIP_MEMORY_SCOPE_AGENT) != (unsigned)(it + 1)) {
          __builtin_amdgcn_s_sleep(8);
        }
      }
      // wave64 lockstep reconvergence: all lanes proceed after ln0's acquire
      float2 prmv = Pg[ln];   // round 0 params, prefetched
      for (int r0 = 0; r0 < 127; ++r0) {
        int r = (s & 1) ? (126 - r0) : r0;
        int p = pair_p(ln, r), q = pair_q(ln, r);
        float2 nxt = prmv;
        if (r0 < 126) nxt = Pg[(r0 + 1) * 64 + ln];   // prefetch next round
        float br = prmv.x, bi = prmv.y;
        float cc = sqrtf(fmaxf(0.0f, 1.0f - br * br - bi * bi));
        float4* Rp = (float4*)(cre + p * RCH);   // 48B rows: 16B-aligned
        float4* Rq = (float4*)(cre + q * RCH);
        float4* Ip = (float4*)(cim + p * RCH);
        float4* Iq = (float4*)(cim + q * RCH);
        float4 pr0 = Rp[0], pr1 = Rp[1], pim0 = Ip[0], pim1 = Ip[1];
        float4 qr0 = Rq[0], qr1 = Rq[1], qim0 = Iq[0], qim1 = Iq[1];
#define ROTC(UPX, UPY, UQX, UQY) { float upx = UPX, upy = UPY, uqx = UQX, uqy = UQY; \
    UPX = cc * upx + (br * uqx + bi * uqy);  /* U_p <- c U_p + conj(sb) U_q */       \
    UPY = cc * upy + (br * uqy - bi * uqx);                                          \
    UQX = cc * uqx - (br * upx - bi * upy);  /* U_q <- c U_q - sb U_p */             \
    UQY = cc * uqy - (br * upy + bi * upx); }
        ROTC(pr0.x, pim0.x, qr0.x, qim0.x)
        ROTC(pr0.y, pim0.y, qr0.y, qim0.y)
        ROTC(pr0.z, pim0.z, qr0.z, qim0.z)
        ROTC(pr0.w, pim0.w, qr0.w, qim0.w)
        ROTC(pr1.x, pim1.x, qr1.x, qim1.x)
        ROTC(pr1.y, pim1.y, qr1.y, qim1.y)
        ROTC(pr1.z, pim1.z, qr1.z, qim1.z)
        ROTC(pr1.w, pim1.w, qr1.w, qim1.w)
#undef ROTC
        Rp[0] = pr0; Rp[1] = pr1; Ip[0] = pim0; Ip[1] = pim1;
        Rq[0] = qr0; Rq[1] = qr1; Iq[0] = qim0; Iq[1] = qim1;
        prmv = nxt;
        __builtin_amdgcn_wave_barrier();
      }
    }
    float2* Ug = U + (size_t)b * NSQ;
    for (int e = ln; e < NDIM * 8; e += 64) {
      int row = e >> 3, c = e & 7;
      Ug[row * NDIM + col0 + c] = make_float2(cre[row * RCH + c], cim[row * RCH + c]);
    }
    return;
  }

  // --------------------------- jacobi path --------------------------------
  // 1024 threads. Per round (ONE barrier): wave0 rotates 128 band blocks
  // (lane ln: d0 (ln,ln) specialized + [ln<=61: d2 (ln,ln+2) | ln==62: (0,1)
  // | ln==63: (62,63)]) then computes P(r+1) (same-wave LDS in-order); waves
  // 1..15 rotate the 1952 rest blocks (d>=3 plus 61 interior d1; 2 each,
  // 32 threads take a 3rd).
  float2* sA2 = (float2*)smem;    // 128 x 130 float2 (AoS re,im)
  __shared__ float4 sprm2[2][64]; // double-buffered {c, br, bi, 0}
  int b = blockIdx.x;
  const float2* Ag = A + (size_t)b * NSQ;
  for (int i = tid; i < NSQ; i += 1024) {
    sA2[(i >> 7) * RSA + (i & 127)] = Ag[i];
  }
  // rest pool: 1891 blocks with d>=3 (triangle order) + 61 interior d1
  // blocks (i,i+1), i=1..61. Threads 64..1023: e, e+960, e+1920 (e<32).
  int nrest = 0;
  int rb_i[3], rb_j[3];
  rb_i[0] = rb_i[1] = rb_i[2] = 0; rb_j[0] = rb_j[1] = rb_j[2] = 0;
  if (tid >= 64) {
#pragma unroll
    for (int m = 0; m < 3; ++m) {
      int e = (tid - 64) + 960 * m;
      if (e < 1952) {
        int bi, bj;
        if (e < 1891) {
          // base(bi) = 61*bi - bi*(bi-1)/2 ; bj = bi + 3 + (e - base)
          int i = 0;
          while (i < 60 && (61 * (i + 1) - ((i + 1) * i) / 2) <= e) ++i;
          bi = i;
          bj = i + 3 + (e - (61 * i - (i * (i - 1)) / 2));
        } else {
          bi = (e - 1891) + 1;   // interior d1: (1,2) .. (61,62)
          bj = bi + 1;
        }
        rb_i[nrest] = bi; rb_j[nrest] = bj;
        ++nrest;
      }
    }
  }
  // wave0 second block: d2 for ln<=61, edge-d1 for lanes 62/63
  int ln = tid;   // valid when tid<64
  int sbi = (ln <= 61) ? ln : ((ln == 62) ? 0 : 62);
  int sbj = (ln <= 61) ? ln + 2 : ((ln == 62) ? 1 : 63);
  __syncthreads();

  for (int s = 0; s < SWEEPS; ++s) {
    float2* Pg = prm + ((size_t)s * BATCH + b) * (127 * 64);
    const bool fwd = !(s & 1);
    const int r_init = fwd ? 0 : 126;
    auto stepP = [&](int x) {
      return fwd ? ((x == 0) ? 0 : ((x == 127) ? 1 : x + 1))
                 : ((x == 0) ? 0 : ((x == 1) ? 127 : x - 1));
    };
    auto stepQ = [&](int x) {
      return fwd ? ((x == 127) ? 1 : x + 1)
                 : ((x == 1) ? 127 : x - 1);
    };
    // wave0 trackers: d0 slot ln; second block slots (sbi,sbj)
    int bp0 = pair_p(ln, r_init), bq0 = pair_q(ln, r_init);
    int sp_i = pair_p(sbi, r_init), sq_i = pair_q(sbi, r_init);
    int sp_j = pair_p(sbj, r_init), sq_j = pair_q(sbj, r_init);
    // rest trackers
    int rpi[3], rqi[3], rpj[3], rqj[3];
#pragma unroll
    for (int m = 0; m < 3; ++m) {
      rpi[m] = pair_p(rb_i[m], r_init); rqi[m] = pair_q(rb_i[m], r_init);
      rpj[m] = pair_p(rb_j[m], r_init); rqj[m] = pair_q(rb_j[m], r_init);
    }
    // param compute helper (wave0 lanes): rows (pp,qq) -> sprm2[buf] + Pg[pos]
    auto pcalc = [&](int pp, int qq, int buf, int pos) {
      float app = sA2[pp * RSA + pp].x, aqq = sA2[qq * RSA + qq].x;
      float2 g = ldc2(sA2, pp, qq);
      float ag2 = g.x * g.x + g.y * g.y;
      float cc = 1.0f, br = 0.0f, bi = 0.0f;
      if (ag2 > 1e-24f) {
        float ag = sqrtf(ag2);
        float ta = (aqq - app) / (2.0f * ag);
        float tt = -copysignf(1.0f, ta) / (fabsf(ta) + sqrtf(1.0f + ta * ta));
        cc = 1.0f / sqrtf(1.0f + tt * tt);
        float tcag = tt * cc / ag;
        br = g.x * tcag; bi = g.y * tcag;
      }
      sprm2[buf][tid] = make_float4(cc, br, bi, 0.0f);
      Pg[pos * 64 + tid] = make_float2(br, bi);   // fire-and-forget
    };
    // generic 2x2 block rotate
    auto rot = [&](int bi_s, int bj_s, int pi_, int qi_, int pj_, int qj_, int buf) {
      float2 B00 = ldc2(sA2, pi_, pj_);
      float2 B01 = ldc2(sA2, pi_, qj_);
      float2 B10 = ldc2(sA2, qi_, pj_);
      float2 B11 = ldc2(sA2, qi_, qj_);
      float4 Pi = sprm2[buf][bi_s], Pj = sprm2[buf][bj_s];
      float ci = Pi.x, bri = Pi.y, bii = Pi.z;
      float cj = Pj.x, brj = Pj.y, bij = Pj.z;
      float t00r = ci * B00.x + (bri * B10.x - bii * B10.y);
      float t00i = ci * B00.y + (bri * B10.y + bii * B10.x);
      float t01r = ci * B01.x + (bri * B11.x - bii * B11.y);
      float t01i = ci * B01.y + (bri * B11.y + bii * B11.x);
      float t10r = ci * B10.x - (bri * B00.x + bii * B00.y);
      float t10i = ci * B10.y - (bri * B00.y - bii * B00.x);
      float t11r = ci * B11.x - (bri * B01.x + bii * B01.y);
      float t11i = ci * B11.y - (bri * B01.y - bii * B01.x);
      stc2(sA2, pi_, pj_,
           cj * t00r + (brj * t01r + bij * t01i),
           cj * t00i + (brj * t01i - bij * t01r));
      stc2(sA2, pi_, qj_,
           cj * t01r - (brj * t00r - bij * t00i),
           cj * t01i - (brj * t00i + bij * t00r));
      stc2(sA2, qi_, pj_,
           cj * t10r + (brj * t11r + bij * t11i),
           cj * t10i + (brj * t11i - bij * t11r));
      stc2(sA2, qi_, qj_,
           cj * t11r - (brj * t10r - bij * t10i),
           cj * t11i - (brj * t10i + bij * t10r));
    };
    // specialized diag-slot rotate (block (ln,ln)): B10 = conj(B01) (same
    // canonical cell -> 1 read saved); the (p,q) store on the 01-path was
    // always overwritten by the 10-path store -> dropped. Bit-exact.
    auto rotd = [&](int pi_, int qi_, int buf) {
      float2 B00 = sA2[pi_ * RSA + pi_];          // diag cells canonical
      float2 B11 = sA2[qi_ * RSA + qi_];
      float2 B01 = ldc2(sA2, pi_, qi_);
      float2 B10 = make_float2(B01.x, -B01.y);
      float4 P = sprm2[buf][ln];
      float ci = P.x, bri = P.y, bii = P.z;
      float t00r = ci * B00.x + (bri * B10.x - bii * B10.y);
      float t00i = ci * B00.y + (bri * B10.y + bii * B10.x);
      float t01r = ci * B01.x + (bri * B11.x - bii * B11.y);
      float t01i = ci * B01.y + (bri * B11.y + bii * B11.x);
      float t10r = ci * B10.x - (bri * B00.x + bii * B00.y);
      float t10i = ci * B10.y - (bri * B00.y - bii * B00.x);
      float t11r = ci * B11.x - (bri * B01.x + bii * B01.y);
      float t11i = ci * B11.y - (bri * B01.y - bii * B01.x);
      stc2(sA2, pi_, pi_,
           ci * t00r + (bri * t01r + bii * t01i),
           ci * t00i + (bri * t01i - bii * t01r));
      stc2(sA2, qi_, pi_,
           ci * t10r + (bri * t11r + bii * t11i),
           ci * t10i + (bri * t11i - bii * t11r));
      stc2(sA2, qi_, qi_,
           ci * t11r - (bri * t10r - bii * t10i),
           ci * t11i - (bri * t10i + bii * t10r));
    };
    // ---- sweep prologue: params for seq(0) into sprm2[0]; init next-rows --
    int ppn = 0, qqn = 0;
    if (tid < 64) {
      int pp0 = pair_p(tid, r_init), qq0 = pair_q(tid, r_init);
      pcalc(pp0, qq0, 0, 0);
      ppn = stepP(pp0); qqn = stepQ(qq0);   // rows at seq(1)
    }
    bar_lgkm();
    int cur = 0;
    // ---- round loop (ONE barrier per round) ----
    for (int r0 = 0; r0 < 127; ++r0) {
      if (tid < 64) {
        rotd(bp0, bq0, cur);                      // d0 block, specialized
        rot(sbi, sbj, sp_i, sq_i, sp_j, sq_j, cur);  // d2 / edge-d1 block
        __builtin_amdgcn_wave_barrier();   // keep compiler order: rots then P
        if (r0 < 126) {
          pcalc(ppn, qqn, cur ^ 1, r0 + 1);  // reads wave0's fresh band cells
          ppn = stepP(ppn); qqn = stepQ(qqn);
        }
      } else {
        // rest blocks: read all cells, compute, write (disjoint cells)
        float2 Bc[3][4];
#pragma unroll
        for (int m = 0; m < 3; ++m) {
          if (m < nrest) {
            Bc[m][0] = ldc2(sA2, rpi[m], rpj[m]);
            Bc[m][1] = ldc2(sA2, rpi[m], rqj[m]);
            Bc[m][2] = ldc2(sA2, rqi[m], rpj[m]);
            Bc[m][3] = ldc2(sA2, rqi[m], rqj[m]);
          }
        }
#pragma unroll
        for (int m = 0; m < 3; ++m) {
          if (m < nrest) {
            float2 B00 = Bc[m][0], B01 = Bc[m][1], B10 = Bc[m][2], B11 = Bc[m][3];
            float4 Pi = sprm2[cur][rb_i[m]], Pj = sprm2[cur][rb_j[m]];
            float ci = Pi.x, bri = Pi.y, bii = Pi.z;
            float cj = Pj.x, brj = Pj.y, bij = Pj.z;
            float t00r = ci * B00.x + (bri * B10.x - bii * B10.y);
            float t00i = ci * B00.y + (bri * B10.y + bii * B10.x);
            float t01r = ci * B01.x + (bri * B11.x - bii * B11.y);
            float t01i = ci * B01.y + (bri * B11.y + bii * B11.x);
            float t10r = ci * B10.x - (bri * B00.x + bii * B00.y);
            float t10i = ci * B10.y - (bri * B00.y - bii * B00.x);
            float t11r = ci * B11.x - (bri * B01.x + bii * B01.y);
            float t11i = ci * B11.y - (bri * B01.y - bii * B01.x);
            stc2(sA2, rpi[m], rpj[m],
                 cj * t00r + (brj * t01r + bij * t01i),
                 cj * t00i + (brj * t01i - bij * t01r));
            stc2(sA2, rpi[m], rqj[m],
                 cj * t01r - (brj * t00r - bij * t00i),
                 cj * t01i - (brj * t00i + bij * t00r));
            stc2(sA2, rqi[m], rpj[m],
                 cj * t10r + (brj * t11r + bij * t11i),
                 cj * t10i + (brj * t11i - bij * t11r));
            stc2(sA2, rqi[m], rqj[m],
                 cj * t11r - (brj * t10r - bij * t10i),
                 cj * t11i - (brj * t10i + bij * t10r));
          }
        }
      }
      bar_lgkm();   // all writes + sprm2[cur^1] visible for next round
      cur ^= 1;
      // step trackers to next round
      bp0 = stepP(bp0); bq0 = stepQ(bq0);
      sp_i = stepP(sp_i); sq_i = stepQ(sq_i);
      sp_j = stepP(sp_j); sq_j = stepQ(sq_j);
#pragma unroll
      for (int m = 0; m < 3; ++m) {
        rpi[m] = stepP(rpi[m]); rqi[m] = stepQ(rqi[m]);
        rpj[m] = stepP(rpj[m]); rqj[m] = stepQ(rqj[m]);
      }
    }
    // publish sweep s params: RELEASE drains wave0's outstanding Pg stores
    // (all issued by wave 0) and performs agent-scope writeback.
    if (tid == 0) {
      __hip_atomic_store(&flags[b * SWEEPS + s], (unsigned)(it + 1),
                         __ATOMIC_RELEASE, __HIP_MEMORY_SCOPE_AGENT);
    }
  }

  // fused rankd (diag is canonical); A is NOT written back (dead after this)
  if (tid < NDIM) {
    float wj = sA2[tid * RSA + tid].x;
    int rank = 0;
    for (int k2 = 0; k2 < NDIM; ++k2) {
      float wk = sA2[k2 * RSA + k2].x;
      rank += (wk < wj) || (wk == wj && k2 < tid);
    }
    double mv = minv[(it * BATCH + b) * NDIM + rank];
    double v = (double)wj + mv;
    if (v < 0.0) v = 0.0;
    d1[b * NDIM + tid] = v;
    d2[b * NDIM + tid] = v - (double)wj;
  }
}

// Theta = V diag(d1) V^H ; Lamda = (1-e/r) Lamda + e * V diag(d2) V^H.
__global__ __launch_bounds__(256) void update_kernel(
    const float2* U, const double* d1, const double* d2,
    const float* rho, const float* eta, int it,
    double2* Theta, double2* Lamda) {
  __shared__ float ViRe[32][33], ViIm[32][33];
  __shared__ float VkRe[32][33], VkIm[32][33];
  __shared__ double s1[32], s2[32];
  int blk = blockIdx.x;
  int b = blk >> 4, tile = blk & 15, ti = tile >> 2, tk = tile & 3;
  int tid = threadIdx.x;
  int lk = tid & 31, lig = tid >> 5;
  double r = (double)rho[it], e = (double)eta[it];
  double a1x[4] = {0, 0, 0, 0}, a1y[4] = {0, 0, 0, 0};
  double a2x[4] = {0, 0, 0, 0}, a2y[4] = {0, 0, 0, 0};
  const float2* Ub = U + (size_t)b * NSQ;
  for (int jc = 0; jc < 4; ++jc) {
    for (int e2 = tid; e2 < 1024; e2 += 256) {
      int rr = e2 & 31, cc2 = e2 >> 5;
      float2 v1 = Ub[(jc * 32 + cc2) * NDIM + ti * 32 + rr];
      ViRe[rr][cc2] = v1.x; ViIm[rr][cc2] = v1.y;
      float2 v2 = Ub[(jc * 32 + cc2) * NDIM + tk * 32 + rr];
      VkRe[rr][cc2] = v2.x; VkIm[rr][cc2] = v2.y;
    }
    if (tid < 32) {
      s1[tid] = d1[b * NDIM + jc * 32 + tid];
      s2[tid] = d2[b * NDIM + jc * 32 + tid];
    }
    __syncthreads();
#pragma unroll
    for (int uo = 0; uo < 4; ++uo) {
      int li = lig + uo * 8;
      double ax = a1x[uo], ay = a1y[uo], bx = a2x[uo], by = a2y[uo];
      for (int jj = 0; jj < 32; ++jj) {
        float var = ViRe[li][jj], vai = ViIm[li][jj];
        float vbr = VkRe[lk][jj], vbi = VkIm[lk][jj];
        double pr = (double)(var * vbr + vai * vbi);
        double pi = (double)(vai * vbr - var * vbi);
        ax += s1[jj] * pr; ay += s1[jj] * pi;
        bx += s2[jj] * pr; by += s2[jj] * pi;
      }
      a1x[uo] = ax; a1y[uo] = ay; a2x[uo] = bx; a2y[uo] = by;
    }
    __syncthreads();
  }
  double lf = 1.0 - e / r;
#pragma unroll
  for (int uo = 0; uo < 4; ++uo) {
    int gi = ti * 32 + lig + uo * 8, gk = tk * 32 + lk;
    size_t idx = (size_t)b * NSQ + gi * NDIM + gk;
    Theta[idx] = make_double2(a1x[uo], a1y[uo]);
    double2 Lold = Lamda[idx];
    Lamda[idx] = make_double2(lf * Lold.x + e * a2x[uo], lf * Lold.y + e * a2y[uo]);
  }
}

// OUTPUT (float32 real parts): T[i][j] = u[|i-j|].re ; uvec.re = u.re
__global__ void writeout_kernel(const double2* u, float* out) {
  int tid = blockIdx.x * 256 + threadIdx.x;
  if (tid >= OUT_ELEMS) return;
  double re;
  if (tid < BATCH * MDIM * MDIM) {
    int b = tid >> 12, rem = tid & 4095, i = rem >> 6, j = rem & 63;
    int d = j - i;
    re = u[b * MDIM + (d >= 0 ? d : -d)].x;
  } else {
    int k2 = tid - BATCH * MDIM * MDIM;
    int b = k2 >> 6, kk = k2 & 63;
    re = u[b * MDIM + kk].x;
  }
  out[tid] = (float)re;
}

// ------------------------------- launch ------------------------------------
extern "C" void kernel_launch(void* const* d_in, const int* in_sizes, int n_in,
                              void* d_out, int out_size, void* d_ws, size_t ws_size,
                              hipStream_t stream) {
  const float* Yre = (const float*)d_in[0];
  const float* Yim = (const float*)d_in[1];
  const float* rho = (const float*)d_in[2];
  const float* tau = (const float*)d_in[3];
  const float* eta = (const float*)d_in[4];
  float* out = (float*)d_out;

  char* ws = (char*)d_ws;
  size_t off = 0;
  auto take = [&](size_t bytes) -> char* {
    char* p = ws + off;
    off += (bytes + 255) & ~(size_t)255;
    return p;
  };
  double2* u     = (double2*)take((size_t)BATCH * MDIM * sizeof(double2));
  double*  minv  = (double*)take((size_t)KITER * BATCH * NDIM * sizeof(double));
  double*  d1    = (double*)take((size_t)BATCH * NDIM * sizeof(double));
  double*  d2    = (double*)take((size_t)BATCH * NDIM * sizeof(double));
  double2* Lamda = (double2*)take((size_t)BATCH * NSQ * sizeof(double2));  // 16.8 MB
  double2* Theta = (double2*)take((size_t)BATCH * NSQ * sizeof(double2));  // 16.8 MB
  float2*  A32   = (float2*)take((size_t)BATCH * NSQ * sizeof(float2));    //  8.4 MB
  float2*  U32   = (float2*)take((size_t)BATCH * NSQ * sizeof(float2));    //  8.4 MB
  float2*  prm   = (float2*)take((size_t)SWEEPS * BATCH * 127 * 64 * sizeof(float2)); // 29.4 MB
  unsigned* flags = (unsigned*)take((size_t)BATCH * SWEEPS * sizeof(unsigned));
  (void)in_sizes; (void)n_in; (void)ws_size; (void)out_size;  // ~80.5 MB total

  hipFuncSetAttribute((const void*)combined_all_kernel,
                      hipFuncAttributeMaxDynamicSharedMemorySize, JAC_LDS_BYTES);

  zero_kernel<<<2048, 256, 0, stream>>>((double*)Theta, (size_t)BATCH * NSQ * 2);
  zero_kernel<<<2048, 256, 0, stream>>>((double*)Lamda, (size_t)BATCH * NSQ * 2);
  flags_zero_kernel<<<1, 512, 0, stream>>>(flags);
  prng_kernel<<<(KITER * BATCH * NDIM + 255) / 256, 256, 0, stream>>>(minv);

  for (int it = 0; it < KITER - 1; ++it) {
    compute_u_kernel<<<16, 256, 0, stream>>>(Theta, Lamda, rho, tau, it, u);
    assemble_kernel<<<BATCH * NSQ / 256, 256, 0, stream>>>(Theta, Lamda, u, Yre, Yim,
                                                           rho, tau, it, A32);
    combined_all_kernel<<<BATCH + 2 * BATCH, 1024, JAC_LDS_BYTES, stream>>>(
        A32, U32, prm, flags, minv, it, d1, d2);
    update_kernel<<<BATCH * 16, 256, 0, stream>>>(U32, d1, d2, rho, eta, it, Theta, Lamda);
  }
  compute_u_kernel<<<16, 256, 0, stream>>>(Theta, Lamda, rho, tau, KITER - 1, u);
  writeout_kernel<<<(OUT_ELEMS + 255) / 256, 256, 0, stream>>>(u, out);
}

// Round 8
// 14914.972 us; speedup vs baseline: 1.1025x; 1.1025x over previous
//
#include <hip/hip_runtime.h>
#include <stdint.h>

// ---------------------------------------------------------------------------
// AnmNetwork: ADMM-like complex PSD iteration. B=64, m=l=64, n=128, K=10.
//  * Sita = V relu(w + minv[rank]) V^H  (second eigh mathematically redundant)
//  * Lamda_new = (1 - eta/rho) Lamda + eta * V diag(relu(w+m)-w) V^H
//  * Output depends only on state entering iteration K-1 -> 9 eigh rounds.
//  * PRNG: JAX threefry2x32 partitionable counters (bit-exact, R5).
// R20 = R18 base (proven 1612us steady) + R19's ownership shrink with a LEAN
// implementation (R19 regressed from VGPR bloat + wave1 straggler, NOT from
// the ownership math):
//  * Wave0: rotd(d0, specialized) + one rot (d2 for ln<=61; edge-d1 (0,1)/
//    (62,63) for lanes 62/63) + pcalc = the exact 128 pcalc-input blocks.
//  * Rest pool 1952 = 1891 d>=3 + 61 interior d1 appended as tail: threads
//    64..1023 take e=t-64 and e+960 -- both ALWAYS valid -> uniform 2
//    blocks/thread, no guards, R18's exact read-8-then-compute path.
//  * The 32 leftover d1 blocks (30,31)..(61,62) go to lanes 0-31 of wave 8
//    (threads 512..543) as a serial 3rd rot -- concentrated so the block
//    max stays at wave0's ~2.75 units.
// State (Theta/Lamda), PRNG, u, writeout stay fp64. SWEEPS=7.
// ---------------------------------------------------------------------------

#define BATCH 64
#define MDIM 64
#define LDIM 64
#define NDIM 128
#define NSQ (NDIM * NDIM)
#define KITER 10
#define SWEEPS 7
#define RSA 130                                 // A row stride (float2 units)
#define JAC_LDS_BYTES (NDIM * RSA * (int)sizeof(float2))   // 133,120 B
#define RCH 12                                  // replay chunk col stride (dwords, 48B)
#define OUT_ELEMS 266240   // 64*64*64 (T) + 64*64 (uvec), f32 real parts

// ----------------------------- threefry2x32 --------------------------------
__device__ __forceinline__ void tf_block(unsigned k0, unsigned k1,
                                         unsigned& x0, unsigned& x1) {
  unsigned k2 = k0 ^ k1 ^ 0x1BD11BDAu;
  x0 += k0; x1 += k1;
#define TF_R(r) { x0 += x1; x1 = (x1 << (r)) | (x1 >> (32 - (r))); x1 ^= x0; }
  TF_R(13) TF_R(15) TF_R(26) TF_R(6)
  x0 += k1; x1 += k2 + 1u;
  TF_R(17) TF_R(29) TF_R(16) TF_R(24)
  x0 += k2; x1 += k0 + 2u;
  TF_R(13) TF_R(15) TF_R(26) TF_R(6)
  x0 += k0; x1 += k1 + 3u;
  TF_R(17) TF_R(29) TF_R(16) TF_R(24)
  x0 += k1; x1 += k2 + 4u;
  TF_R(13) TF_R(15) TF_R(26) TF_R(6)
  x0 += k2; x1 += k0 + 5u;
#undef TF_R
}

// ------------------------------- erfinv (f64) ------------------------------
__device__ double erfinv_d(double x) {
  double w = -log1p(-x * x);
  double p;
  if (w < 6.25) {
    w -= 3.125;
    const double c[23] = {
      -3.6444120640178196996e-21, -1.685059138182016589e-19,
      1.2858480715256400167e-18,  1.115787767802518096e-17,
      -1.333171662854620906e-16,  2.0972767875968561637e-17,
      6.6376381343583238325e-15,  -4.0545662729752068639e-14,
      -8.1519341976054721522e-14, 2.6335093153082322977e-12,
      -1.2975133253453532498e-11, -5.4154120542946279317e-11,
      1.051212273321532285e-09,   -4.1126339803469836976e-09,
      -2.9070369957882005086e-08, 4.2347877827932403518e-07,
      -1.3654692000834678645e-06, -1.3882523362786468719e-05,
      1.8673420803405714802e-04,  -7.4070253416626697512e-04,
      -6.0336708714301490533e-03, 2.4015818242558961693e-01,
      1.6536545626831027356e+00};
    p = c[0];
#pragma unroll
    for (int i = 1; i < 23; ++i) p = p * w + c[i];
  } else if (w < 16.0) {
    double s = sqrt(w) - 3.25;
    const double c[19] = {
      2.2137376921775787049e-09,  9.0756561938885390979e-08,
      -2.7517406297064545428e-07, 1.8239629214389227755e-08,
      1.5027403968909827627e-06,  -4.013867526981545969e-06,
      2.9234449089955446044e-06,  1.2475304481671778723e-05,
      -4.7318229009055733981e-05, 6.8284851459573175448e-05,
      2.4031110387097893999e-05,  -3.5503752036284748449e-04,
      9.5328937973738049703e-04,  -1.6882755560235047313e-03,
      2.4914420961078508066e-03,  -3.7512085075692412107e-03,
      5.3709145535900636051e-03,  1.0052589676941592334e+00,
      3.0838856104922207635e+00};
    p = c[0];
#pragma unroll
    for (int i = 1; i < 19; ++i) p = p * s + c[i];
  } else {
    double s = sqrt(w) - 5.0;
    const double c[17] = {
      -2.7109920616438573243e-11, -2.5556418169965252055e-10,
      1.5076572693500548083e-09,  -3.7894654401267369937e-09,
      7.6157012080783393804e-09,  -1.4960026627149240478e-08,
      2.9147953450901080826e-08,  -6.7711997758452339498e-08,
      2.2900482228026654717e-07,  -9.9298272942317002539e-07,
      4.5260625972231537039e-06,  -1.9681778105531670567e-05,
      7.5995277030017761139e-05,  -2.1503011930044477347e-04,
      -1.3871931833623122026e-04, 1.0103004648645343977e+00,
      4.8499064014085844221e+00};
    p = c[0];
#pragma unroll
    for (int i = 1; i < 17; ++i) p = p * s + c[i];
  }
  double z = p * x;
  const double spi2 = 0.8862269254527580;  // sqrt(pi)/2
  double ax = fabs(x);
#pragma unroll
  for (int nr = 0; nr < 2; ++nr) {
    if (ax > 0.9375) {
      double az = fabs(z);
      double corr = (erfc(az) - (1.0 - ax)) * spi2 * exp(az * az);
      az += corr;
      z = copysign(az, x);
    } else {
      z -= (erf(z) - x) * spi2 * exp(z * z);
    }
  }
  return z;
}

// ------------------------------- kernels -----------------------------------
__global__ void zero_kernel(double* p, size_t n) {
  size_t i = (size_t)blockIdx.x * blockDim.x + threadIdx.x;
  size_t stride = (size_t)gridDim.x * blockDim.x;
  for (; i < n; i += stride) p[i] = 0.0;
}

__global__ void flags_zero_kernel(unsigned* flags) {
  int tid = threadIdx.x;
  if (tid < BATCH * SWEEPS) flags[tid] = 0u;
}

__global__ void prng_kernel(double* minv) {
  int tid = blockIdx.x * blockDim.x + threadIdx.x;
  if (tid >= KITER * BATCH * NDIM) return;
  int it = tid / (BATCH * NDIM);
  int i = tid % (BATCH * NDIM);
  unsigned nk0 = 0u, nk1 = (unsigned)it;
  tf_block(0u, 42u, nk0, nk1);                       // fold_in
  unsigned c0 = 0u, c1 = (unsigned)i;                // partitionable counter
  tf_block(nk0, nk1, c0, c1);
  unsigned long long bits = ((unsigned long long)c0 << 32) | (unsigned long long)c1;
  unsigned long long fb = (bits >> 12) | 0x3FF0000000000000ull;
  double f = __builtin_bit_cast(double, fb) - 1.0;
  const double lo = __builtin_bit_cast(double, 0xBFEFFFFFFFFFFFFFull);
  double uu = f * 2.0 + lo;
  if (uu < lo) uu = lo;
  minv[tid] = 1.4142135623730951 * erfinv_d(uu);
}

__global__ void compute_u_kernel(const double2* Theta, const double2* Lamda,
                                 const float* rho, const float* tau, int it,
                                 double2* u) {
  int tid = blockIdx.x * blockDim.x + threadIdx.x;
  if (tid >= BATCH * MDIM) return;
  int b = tid / MDIM, kk = tid % MDIM;
  double r = (double)rho[it], t = (double)tau[it];
  const double2* Lb = Lamda + (size_t)b * NSQ;
  const double2* Tb = Theta + (size_t)b * NSQ;
  double ar = 0.0, ai = 0.0;
  for (int i = 0; i + kk < MDIM; ++i) {
    double2 L = Lb[i * NDIM + i + kk];
    double2 Th = Tb[i * NDIM + i + kk];
    ar += L.x + r * Th.x;
    ai += L.y + r * Th.y;
  }
  if (kk == 0) ar += -(t * 0.5) * (double)MDIM;
  double s = 1.0 / ((double)(MDIM - kk) * r);
  u[b * MDIM + kk] = make_double2(ar * s, ai * s);
}

// A32 = fp32(StackM - Lamda/r)   (U init lives in combined_all: U = I)
__global__ void assemble_kernel(const double2* Theta, const double2* Lamda,
                                const double2* u, const float* Yre, const float* Yim,
                                const float* rho, const float* tau, int it,
                                float2* A32) {
  int tid = blockIdx.x * 256 + threadIdx.x;
  if (tid >= BATCH * NSQ) return;
  int b = tid / NSQ, rem = tid % NSQ, i = rem / NDIM, j = rem % NDIM;
  double r = (double)rho[it], t = (double)tau[it];
  size_t idx = (size_t)b * NSQ + rem;
  double2 L = Lamda[idx], Th = Theta[idx];
  double axr, axi;
  if (i < MDIM && j < MDIM) {
    int d = j - i;
    double2 uv = u[b * MDIM + (d >= 0 ? d : -d)];
    double uy = (d >= 0) ? uv.y : -uv.y;
    axr = uv.x - L.x / r;
    axi = uy - L.y / r;
  } else if (i < MDIM) {
    double yr = (double)Yre[(b * MDIM + i) * LDIM + (j - MDIM)];
    double yi = (double)Yim[(b * MDIM + i) * LDIM + (j - MDIM)];
    double inv = 1.0 / (1.0 + 2.0 * r);
    axr = (yr + 2.0 * L.x + 2.0 * r * Th.x) * inv - L.x / r;
    axi = (yi + 2.0 * L.y + 2.0 * r * Th.y) * inv - L.y / r;
  } else if (j < MDIM) {
    double yr = (double)Yre[(b * MDIM + j) * LDIM + (i - MDIM)];
    double yi = -(double)Yim[(b * MDIM + j) * LDIM + (i - MDIM)];
    double inv = 1.0 / (1.0 + 2.0 * r);
    axr = (yr + 2.0 * L.x + 2.0 * r * Th.x) * inv - L.x / r;
    axi = (yi + 2.0 * L.y + 2.0 * r * Th.y) * inv - L.y / r;
  } else {
    axr = Th.x - ((i == j) ? t / (2.0 * r) : 0.0);
    axi = Th.y;
  }
  A32[idx] = make_float2((float)axr, (float)axi);
}

__device__ __forceinline__ int pair_p(int j, int r) {
  return (j == 0) ? 0 : 1 + (j - 1 + r) % 127;
}
__device__ __forceinline__ int pair_q(int j, int r) {
  return 1 + (126 - j + r) % 127;
}

// Canonical-upper accessors (AoS float2 plane, stride RSA) -> single b64 op.
__device__ __forceinline__ float2 ldc2(const float2* sA, int r, int c) {
  int rr = r <= c ? r : c, cc = r <= c ? c : r;
  float2 v = sA[rr * RSA + cc];
  if (r > c) v.y = -v.y;
  return v;
}
__device__ __forceinline__ void stc2(float2* sA, int r, int c, float zr, float zi) {
  int rr = r <= c ? r : c, cc = r <= c ? c : r;
  sA[rr * RSA + cc] = make_float2(zr, (r <= c) ? zi : -zi);
}

// Raw barrier: drain own LDS ops only -- wave0's Pg global stores stay in
// flight (drained once per sweep by the RELEASE atomic on the same wave).
__device__ __forceinline__ void bar_lgkm() {
  asm volatile("s_waitcnt lgkmcnt(0)" ::: "memory");
  __builtin_amdgcn_s_barrier();
}

// Fused dispatch: blocks 0..63 jacobi (all 7 sweeps, A LDS-resident, params
// released per sweep via device-scope flags); blocks 64..191 replay (U chunk
// LDS-resident across all 7 sweeps, init to I, acquire-spin per sweep).
__global__ __launch_bounds__(1024) void combined_all_kernel(
    const float2* __restrict__ A, float2* __restrict__ U,
    float2* __restrict__ prm,        // [SWEEPS][BATCH][127][64]
    unsigned* __restrict__ flags,    // [BATCH][SWEEPS]
    const double* __restrict__ minv, int it,
    double* __restrict__ d1, double* __restrict__ d2) {
  extern __shared__ float smem[];
  int tid = threadIdx.x;

  if (blockIdx.x >= BATCH) {
    // ------------------------- replay path --------------------------------
    if (tid >= 512) return;   // 8 working waves; no block barriers here
    int rb = blockIdx.x - BATCH;
    int wv = tid >> 6, ln = tid & 63;
    int b = rb >> 1, half = rb & 1;
    int col0 = (half * 8 + wv) * 8;
    float* cre = smem + wv * (2 * NDIM * RCH);
    float* cim = cre + NDIM * RCH;
    // U = I (chunk init in LDS; no global load)
    for (int e = ln; e < NDIM * 8; e += 64) {
      int row = e >> 3, c = e & 7;
      cre[row * RCH + c] = (row == col0 + c) ? 1.0f : 0.0f;
      cim[row * RCH + c] = 0.0f;
    }
    for (int s = 0; s < SWEEPS; ++s) {
      const float2* Pg = prm + ((size_t)s * BATCH + b) * (127 * 64);
      if (ln == 0) {   // per-wave acquire spin (waves are independent)
        while (__hip_atomic_load(&flags[b * SWEEPS + s], __ATOMIC_ACQUIRE,
                                 __HIP_MEMORY_SCOPE_AGENT) != (unsigned)(it + 1)) {
          __builtin_amdgcn_s_sleep(8);
        }
      }
      // wave64 lockstep reconvergence: all lanes proceed after ln0's acquire
      float2 prmv = Pg[ln];   // round 0 params, prefetched
      for (int r0 = 0; r0 < 127; ++r0) {
        int r = (s & 1) ? (126 - r0) : r0;
        int p = pair_p(ln, r), q = pair_q(ln, r);
        float2 nxt = prmv;
        if (r0 < 126) nxt = Pg[(r0 + 1) * 64 + ln];   // prefetch next round
        float br = prmv.x, bi = prmv.y;
        float cc = sqrtf(fmaxf(0.0f, 1.0f - br * br - bi * bi));
        float4* Rp = (float4*)(cre + p * RCH);   // 48B rows: 16B-aligned
        float4* Rq = (float4*)(cre + q * RCH);
        float4* Ip = (float4*)(cim + p * RCH);
        float4* Iq = (float4*)(cim + q * RCH);
        float4 pr0 = Rp[0], pr1 = Rp[1], pim0 = Ip[0], pim1 = Ip[1];
        float4 qr0 = Rq[0], qr1 = Rq[1], qim0 = Iq[0], qim1 = Iq[1];
#define ROTC(UPX, UPY, UQX, UQY) { float upx = UPX, upy = UPY, uqx = UQX, uqy = UQY; \
    UPX = cc * upx + (br * uqx + bi * uqy);  /* U_p <- c U_p + conj(sb) U_q */       \
    UPY = cc * upy + (br * uqy - bi * uqx);                                          \
    UQX = cc * uqx - (br * upx - bi * upy);  /* U_q <- c U_q - sb U_p */             \
    UQY = cc * uqy - (br * upy + bi * upx); }
        ROTC(pr0.x, pim0.x, qr0.x, qim0.x)
        ROTC(pr0.y, pim0.y, qr0.y, qim0.y)
        ROTC(pr0.z, pim0.z, qr0.z, qim0.z)
        ROTC(pr0.w, pim0.w, qr0.w, qim0.w)
        ROTC(pr1.x, pim1.x, qr1.x, qim1.x)
        ROTC(pr1.y, pim1.y, qr1.y, qim1.y)
        ROTC(pr1.z, pim1.z, qr1.z, qim1.z)
        ROTC(pr1.w, pim1.w, qr1.w, qim1.w)
#undef ROTC
        Rp[0] = pr0; Rp[1] = pr1; Ip[0] = pim0; Ip[1] = pim1;
        Rq[0] = qr0; Rq[1] = qr1; Iq[0] = qim0; Iq[1] = qim1;
        prmv = nxt;
        __builtin_amdgcn_wave_barrier();
      }
    }
    float2* Ug = U + (size_t)b * NSQ;
    for (int e = ln; e < NDIM * 8; e += 64) {
      int row = e >> 3, c = e & 7;
      Ug[row * NDIM + col0 + c] = make_float2(cre[row * RCH + c], cim[row * RCH + c]);
    }
    return;
  }

  // --------------------------- jacobi path --------------------------------
  // 1024 threads. Per round (ONE barrier): wave0 rotd(d0) + rot(d2/edge-d1)
  // then pcalc(r+1) (same-wave LDS in-order); waves 1..15 rotate 2 rest
  // blocks each (uniform); lanes 0..31 of wave 8 take a serial 3rd block.
  float2* sA2 = (float2*)smem;    // 128 x 130 float2 (AoS re,im)
  __shared__ float4 sprm2[2][64]; // double-buffered {c, br, bi, 0}
  int b = blockIdx.x;
  const float2* Ag = A + (size_t)b * NSQ;
  for (int i = tid; i < NSQ; i += 1024) {
    sA2[(i >> 7) * RSA + (i & 127)] = Ag[i];
  }
  // rest pool (1952): e<1891 -> d>=3 triangle; e>=1891 -> interior d1
  // (bi = e-1890, bj = bi+1, covering (1,2)..(61,62)).
  auto decode_rest = [&](int e, int& bi, int& bj) {
    if (e < 1891) {
      int i = 0;
      while (i < 60 && (61 * (i + 1) - ((i + 1) * i) / 2) <= e) ++i;
      bi = i;
      bj = i + 3 + (e - (61 * i - (i * (i - 1)) / 2));
    } else {
      bi = e - 1890;
      bj = bi + 1;
    }
  };
  int rb_i[2], rb_j[2];
  rb_i[0] = rb_i[1] = 0; rb_j[0] = rb_j[1] = 0;
  if (tid >= 64) {
    decode_rest(tid - 64, rb_i[0], rb_j[0]);
    decode_rest(tid - 64 + 960, rb_i[1], rb_j[1]);
  }
  // third block: lanes 0..31 of wave 8 (threads 512..543), e3 in [1920,1952)
  bool has3 = (tid >= 512 && tid < 544);
  int tb_i = 0, tb_j = 0;
  if (has3) decode_rest(1920 + (tid - 512), tb_i, tb_j);
  // wave0 second block: d2 for ln<=61, edge-d1 for lanes 62/63
  int ln = tid;   // valid when tid<64
  int sbi = (ln <= 61) ? ln : ((ln == 62) ? 0 : 62);
  int sbj = (ln <= 61) ? ln + 2 : ((ln == 62) ? 1 : 63);
  __syncthreads();

  for (int s = 0; s < SWEEPS; ++s) {
    float2* Pg = prm + ((size_t)s * BATCH + b) * (127 * 64);
    const bool fwd = !(s & 1);
    const int r_init = fwd ? 0 : 126;
    auto stepP = [&](int x) {
      return fwd ? ((x == 0) ? 0 : ((x == 127) ? 1 : x + 1))
                 : ((x == 0) ? 0 : ((x == 1) ? 127 : x - 1));
    };
    auto stepQ = [&](int x) {
      return fwd ? ((x == 127) ? 1 : x + 1)
                 : ((x == 1) ? 127 : x - 1);
    };
    // wave0 trackers: d0 slot ln; second block slots (sbi,sbj)
    int bp0 = pair_p(ln, r_init), bq0 = pair_q(ln, r_init);
    int sp_i = pair_p(sbi, r_init), sq_i = pair_q(sbi, r_init);
    int sp_j = pair_p(sbj, r_init), sq_j = pair_q(sbj, r_init);
    // rest trackers (+ third block)
    int rpi[2], rqi[2], rpj[2], rqj[2];
#pragma unroll
    for (int m = 0; m < 2; ++m) {
      rpi[m] = pair_p(rb_i[m], r_init); rqi[m] = pair_q(rb_i[m], r_init);
      rpj[m] = pair_p(rb_j[m], r_init); rqj[m] = pair_q(rb_j[m], r_init);
    }
    int tpi = pair_p(tb_i, r_init), tqi = pair_q(tb_i, r_init);
    int tpj = pair_p(tb_j, r_init), tqj = pair_q(tb_j, r_init);
    // param compute helper (wave0 lanes): rows (pp,qq) -> sprm2[buf] + Pg[pos]
    auto pcalc = [&](int pp, int qq, int buf, int pos) {
      float app = sA2[pp * RSA + pp].x, aqq = sA2[qq * RSA + qq].x;
      float2 g = ldc2(sA2, pp, qq);
      float ag2 = g.x * g.x + g.y * g.y;
      float cc = 1.0f, br = 0.0f, bi = 0.0f;
      if (ag2 > 1e-24f) {
        float ag = sqrtf(ag2);
        float ta = (aqq - app) / (2.0f * ag);
        float tt = -copysignf(1.0f, ta) / (fabsf(ta) + sqrtf(1.0f + ta * ta));
        cc = 1.0f / sqrtf(1.0f + tt * tt);
        float tcag = tt * cc / ag;
        br = g.x * tcag; bi = g.y * tcag;
      }
      sprm2[buf][tid] = make_float4(cc, br, bi, 0.0f);
      Pg[pos * 64 + tid] = make_float2(br, bi);   // fire-and-forget
    };
    // generic 2x2 block rotate (read-compute-write serial)
    auto rot = [&](int bi_s, int bj_s, int pi_, int qi_, int pj_, int qj_, int buf) {
      float2 B00 = ldc2(sA2, pi_, pj_);
      float2 B01 = ldc2(sA2, pi_, qj_);
      float2 B10 = ldc2(sA2, qi_, pj_);
      float2 B11 = ldc2(sA2, qi_, qj_);
      float4 Pi = sprm2[buf][bi_s], Pj = sprm2[buf][bj_s];
      float ci = Pi.x, bri = Pi.y, bii = Pi.z;
      float cj = Pj.x, brj = Pj.y, bij = Pj.z;
      float t00r = ci * B00.x + (bri * B10.x - bii * B10.y);
      float t00i = ci * B00.y + (bri * B10.y + bii * B10.x);
      float t01r = ci * B01.x + (bri * B11.x - bii * B11.y);
      float t01i = ci * B01.y + (bri * B11.y + bii * B11.x);
      float t10r = ci * B10.x - (bri * B00.x + bii * B00.y);
      float t10i = ci * B10.y - (bri * B00.y - bii * B00.x);
      float t11r = ci * B11.x - (bri * B01.x + bii * B01.y);
      float t11i = ci * B11.y - (bri * B01.y - bii * B01.x);
      stc2(sA2, pi_, pj_,
           cj * t00r + (brj * t01r + bij * t01i),
           cj * t00i + (brj * t01i - bij * t01r));
      stc2(sA2, pi_, qj_,
           cj * t01r - (brj * t00r - bij * t00i),
           cj * t01i - (brj * t00i + bij * t00r));
      stc2(sA2, qi_, pj_,
           cj * t10r + (brj * t11r + bij * t11i),
           cj * t10i + (brj * t11i - bij * t11r));
      stc2(sA2, qi_, qj_,
           cj * t11r - (brj * t10r - bij * t10i),
           cj * t11i - (brj * t10i + bij * t10r));
    };
    // specialized diag-slot rotate (block (ln,ln)): B10 = conj(B01) (same
    // canonical cell -> 1 read saved); the (p,q) store on the 01-path was
    // always overwritten by the 10-path store -> dropped. Bit-exact.
    auto rotd = [&](int pi_, int qi_, int buf) {
      float2 B00 = sA2[pi_ * RSA + pi_];          // diag cells canonical
      float2 B11 = sA2[qi_ * RSA + qi_];
      float2 B01 = ldc2(sA2, pi_, qi_);
      float2 B10 = make_float2(B01.x, -B01.y);
      float4 P = sprm2[buf][ln];
      float ci = P.x, bri = P.y, bii = P.z;
      float t00r = ci * B00.x + (bri * B10.x - bii * B10.y);
      float t00i = ci * B00.y + (bri * B10.y + bii * B10.x);
      float t01r = ci * B01.x + (bri * B11.x - bii * B11.y);
      float t01i = ci * B01.y + (bri * B11.y + bii * B11.x);
      float t10r = ci * B10.x - (bri * B00.x + bii * B00.y);
      float t10i = ci * B10.y - (bri * B00.y - bii * B00.x);
      float t11r = ci * B11.x - (bri * B01.x + bii * B01.y);
      float t11i = ci * B11.y - (bri * B01.y - bii * B01.x);
      stc2(sA2, pi_, pi_,
           ci * t00r + (bri * t01r + bii * t01i),
           ci * t00i + (bri * t01i - bii * t01r));
      stc2(sA2, qi_, pi_,
           ci * t10r + (bri * t11r + bii * t11i),
           ci * t10i + (bri * t11i - bii * t11r));
      stc2(sA2, qi_, qi_,
           ci * t11r - (bri * t10r - bii * t10i),
           ci * t11i - (bri * t10i + bii * t10r));
    };
    // ---- sweep prologue: params for seq(0) into sprm2[0]; init next-rows --
    int ppn = 0, qqn = 0;
    if (tid < 64) {
      int pp0 = pair_p(tid, r_init), qq0 = pair_q(tid, r_init);
      pcalc(pp0, qq0, 0, 0);
      ppn = stepP(pp0); qqn = stepQ(qq0);   // rows at seq(1)
    }
    bar_lgkm();
    int cur = 0;
    // ---- round loop (ONE barrier per round) ----
    for (int r0 = 0; r0 < 127; ++r0) {
      if (tid < 64) {
        rotd(bp0, bq0, cur);                      // d0 block, specialized
        rot(sbi, sbj, sp_i, sq_i, sp_j, sq_j, cur);  // d2 / edge-d1 block
        __builtin_amdgcn_wave_barrier();   // keep compiler order: rots then P
        if (r0 < 126) {
          pcalc(ppn, qqn, cur ^ 1, r0 + 1);  // reads wave0's fresh band cells
          ppn = stepP(ppn); qqn = stepQ(qqn);
        }
      } else {
        // two rest blocks: read all 8 cells, compute, write 8 (R18 pattern)
        float2 B00a = ldc2(sA2, rpi[0], rpj[0]);
        float2 B01a = ldc2(sA2, rpi[0], rqj[0]);
        float2 B10a = ldc2(sA2, rqi[0], rpj[0]);
        float2 B11a = ldc2(sA2, rqi[0], rqj[0]);
        float2 B00b = ldc2(sA2, rpi[1], rpj[1]);
        float2 B01b = ldc2(sA2, rpi[1], rqj[1]);
        float2 B10b = ldc2(sA2, rqi[1], rpj[1]);
        float2 B11b = ldc2(sA2, rqi[1], rqj[1]);
        {
          float4 Pi = sprm2[cur][rb_i[0]], Pj = sprm2[cur][rb_j[0]];
          float ci = Pi.x, bri = Pi.y, bii = Pi.z;
          float cj = Pj.x, brj = Pj.y, bij = Pj.z;
          float t00r = ci * B00a.x + (bri * B10a.x - bii * B10a.y);
          float t00i = ci * B00a.y + (bri * B10a.y + bii * B10a.x);
          float t01r = ci * B01a.x + (bri * B11a.x - bii * B11a.y);
          float t01i = ci * B01a.y + (bri * B11a.y + bii * B11a.x);
          float t10r = ci * B10a.x - (bri * B00a.x + bii * B00a.y);
          float t10i = ci * B10a.y - (bri * B00a.y - bii * B00a.x);
          float t11r = ci * B11a.x - (bri * B01a.x + bii * B01a.y);
          float t11i = ci * B11a.y - (bri * B01a.y - bii * B01a.x);
          stc2(sA2, rpi[0], rpj[0],
               cj * t00r + (brj * t01r + bij * t01i),
               cj * t00i + (brj * t01i - bij * t01r));
          stc2(sA2, rpi[0], rqj[0],
               cj * t01r - (brj * t00r - bij * t00i),
               cj * t01i - (brj * t00i + bij * t00r));
          stc2(sA2, rqi[0], rpj[0],
               cj * t10r + (brj * t11r + bij * t11i),
               cj * t10i + (brj * t11i - bij * t11r));
          stc2(sA2, rqi[0], rqj[0],
               cj * t11r - (brj * t10r - bij * t10i),
               cj * t11i - (brj * t10i + bij * t10r));
        }
        {
          float4 Pi = sprm2[cur][rb_i[1]], Pj = sprm2[cur][rb_j[1]];
          float ci = Pi.x, bri = Pi.y, bii = Pi.z;
          float cj = Pj.x, brj = Pj.y, bij = Pj.z;
          float t00r = ci * B00b.x + (bri * B10b.x - bii * B10b.y);
          float t00i = ci * B00b.y + (bri * B10b.y + bii * B10b.x);
          float t01r = ci * B01b.x + (bri * B11b.x - bii * B11b.y);
          float t01i = ci * B01b.y + (bri * B11b.y + bii * B11b.x);
          float t10r = ci * B10b.x - (bri * B00b.x + bii * B00b.y);
          float t10i = ci * B10b.y - (bri * B00b.y - bii * B00b.x);
          float t11r = ci * B11b.x - (bri * B01b.x + bii * B01b.y);
          float t11i = ci * B11b.y - (bri * B01b.y - bii * B01b.x);
          stc2(sA2, rpi[1], rpj[1],
               cj * t00r + (brj * t01r + bij * t01i),
               cj * t00i + (brj * t01i - bij * t01r));
          stc2(sA2, rpi[1], rqj[1],
               cj * t01r - (brj * t00r - bij * t00i),
               cj * t01i - (brj * t00i + bij * t00r));
          stc2(sA2, rqi[1], rpj[1],
               cj * t10r + (brj * t11r + bij * t11i),
               cj * t10i + (brj * t11i - bij * t11r));
          stc2(sA2, rqi[1], rqj[1],
               cj * t11r - (brj * t10r - bij * t10i),
               cj * t11i - (brj * t10i + bij * t10r));
        }
        if (has3) rot(tb_i, tb_j, tpi, tqi, tpj, tqj, cur);
      }
      bar_lgkm();   // all writes + sprm2[cur^1] visible for next round
      cur ^= 1;
      // step trackers to next round
      bp0 = stepP(bp0); bq0 = stepQ(bq0);
      sp_i = stepP(sp_i); sq_i = stepQ(sq_i);
      sp_j = stepP(sp_j); sq_j = stepQ(sq_j);
#pragma unroll
      for (int m = 0; m < 2; ++m) {
        rpi[m] = stepP(rpi[m]); rqi[m] = stepQ(rqi[m]);
        rpj[m] = stepP(rpj[m]); rqj[m] = stepQ(rqj[m]);
      }
      tpi = stepP(tpi); tqi = stepQ(tqi);
      tpj = stepP(tpj); tqj = stepQ(tqj);
    }
    // publish sweep s params: RELEASE drains wave0's outstanding Pg stores
    // (all issued by wave 0) and performs agent-scope writeback.
    if (tid == 0) {
      __hip_atomic_store(&flags[b * SWEEPS + s], (unsigned)(it + 1),
                         __ATOMIC_RELEASE, __HIP_MEMORY_SCOPE_AGENT);
    }
  }

  // fused rankd (diag is canonical); A is NOT written back (dead after this)
  if (tid < NDIM) {
    float wj = sA2[tid * RSA + tid].x;
    int rank = 0;
    for (int k2 = 0; k2 < NDIM; ++k2) {
      float wk = sA2[k2 * RSA + k2].x;
      rank += (wk < wj) || (wk == wj && k2 < tid);
    }
    double mv = minv[(it * BATCH + b) * NDIM + rank];
    double v = (double)wj + mv;
    if (v < 0.0) v = 0.0;
    d1[b * NDIM + tid] = v;
    d2[b * NDIM + tid] = v - (double)wj;
  }
}

// Theta = V diag(d1) V^H ; Lamda = (1-e/r) Lamda + e * V diag(d2) V^H.
__global__ __launch_bounds__(256) void update_kernel(
    const float2* U, const double* d1, const double* d2,
    const float* rho, const float* eta, int it,
    double2* Theta, double2* Lamda) {
  __shared__ float ViRe[32][33], ViIm[32][33];
  __shared__ float VkRe[32][33], VkIm[32][33];
  __shared__ double s1[32], s2[32];
  int blk = blockIdx.x;
  int b = blk >> 4, tile = blk & 15, ti = tile >> 2, tk = tile & 3;
  int tid = threadIdx.x;
  int lk = tid & 31, lig = tid >> 5;
  double r = (double)rho[it], e = (double)eta[it];
  double a1x[4] = {0, 0, 0, 0}, a1y[4] = {0, 0, 0, 0};
  double a2x[4] = {0, 0, 0, 0}, a2y[4] = {0, 0, 0, 0};
  const float2* Ub = U + (size_t)b * NSQ;
  for (int jc = 0; jc < 4; ++jc) {
    for (int e2 = tid; e2 < 1024; e2 += 256) {
      int rr = e2 & 31, cc2 = e2 >> 5;
      float2 v1 = Ub[(jc * 32 + cc2) * NDIM + ti * 32 + rr];
      ViRe[rr][cc2] = v1.x; ViIm[rr][cc2] = v1.y;
      float2 v2 = Ub[(jc * 32 + cc2) * NDIM + tk * 32 + rr];
      VkRe[rr][cc2] = v2.x; VkIm[rr][cc2] = v2.y;
    }
    if (tid < 32) {
      s1[tid] = d1[b * NDIM + jc * 32 + tid];
      s2[tid] = d2[b * NDIM + jc * 32 + tid];
    }
    __syncthreads();
#pragma unroll
    for (int uo = 0; uo < 4; ++uo) {
      int li = lig + uo * 8;
      double ax = a1x[uo], ay = a1y[uo], bx = a2x[uo], by = a2y[uo];
      for (int jj = 0; jj < 32; ++jj) {
        float var = ViRe[li][jj], vai = ViIm[li][jj];
        float vbr = VkRe[lk][jj], vbi = VkIm[lk][jj];
        double pr = (double)(var * vbr + vai * vbi);
        double pi = (double)(vai * vbr - var * vbi);
        ax += s1[jj] * pr; ay += s1[jj] * pi;
        bx += s2[jj] * pr; by += s2[jj] * pi;
      }
      a1x[uo] = ax; a1y[uo] = ay; a2x[uo] = bx; a2y[uo] = by;
    }
    __syncthreads();
  }
  double lf = 1.0 - e / r;
#pragma unroll
  for (int uo = 0; uo < 4; ++uo) {
    int gi = ti * 32 + lig + uo * 8, gk = tk * 32 + lk;
    size_t idx = (size_t)b * NSQ + gi * NDIM + gk;
    Theta[idx] = make_double2(a1x[uo], a1y[uo]);
    double2 Lold = Lamda[idx];
    Lamda[idx] = make_double2(lf * Lold.x + e * a2x[uo], lf * Lold.y + e * a2y[uo]);
  }
}

// OUTPUT (float32 real parts): T[i][j] = u[|i-j|].re ; uvec.re = u.re
__global__ void writeout_kernel(const double2* u, float* out) {
  int tid = blockIdx.x * 256 + threadIdx.x;
  if (tid >= OUT_ELEMS) return;
  double re;
  if (tid < BATCH * MDIM * MDIM) {
    int b = tid >> 12, rem = tid & 4095, i = rem >> 6, j = rem & 63;
    int d = j - i;
    re = u[b * MDIM + (d >= 0 ? d : -d)].x;
  } else {
    int k2 = tid - BATCH * MDIM * MDIM;
    int b = k2 >> 6, kk = k2 & 63;
    re = u[b * MDIM + kk].x;
  }
  out[tid] = (float)re;
}

// ------------------------------- launch ------------------------------------
extern "C" void kernel_launch(void* const* d_in, const int* in_sizes, int n_in,
                              void* d_out, int out_size, void* d_ws, size_t ws_size,
                              hipStream_t stream) {
  const float* Yre = (const float*)d_in[0];
  const float* Yim = (const float*)d_in[1];
  const float* rho = (const float*)d_in[2];
  const float* tau = (const float*)d_in[3];
  const float* eta = (const float*)d_in[4];
  float* out = (float*)d_out;

  char* ws = (char*)d_ws;
  size_t off = 0;
  auto take = [&](size_t bytes) -> char* {
    char* p = ws + off;
    off += (bytes + 255) & ~(size_t)255;
    return p;
  };
  double2* u     = (double2*)take((size_t)BATCH * MDIM * sizeof(double2));
  double*  minv  = (double*)take((size_t)KITER * BATCH * NDIM * sizeof(double));
  double*  d1    = (double*)take((size_t)BATCH * NDIM * sizeof(double));
  double*  d2    = (double*)take((size_t)BATCH * NDIM * sizeof(double));
  double2* Lamda = (double2*)take((size_t)BATCH * NSQ * sizeof(double2));  // 16.8 MB
  double2* Theta = (double2*)take((size_t)BATCH * NSQ * sizeof(double2));  // 16.8 MB
  float2*  A32   = (float2*)take((size_t)BATCH * NSQ * sizeof(float2));    //  8.4 MB
  float2*  U32   = (float2*)take((size_t)BATCH * NSQ * sizeof(float2));    //  8.4 MB
  float2*  prm   = (float2*)take((size_t)SWEEPS * BATCH * 127 * 64 * sizeof(float2)); // 29.4 MB
  unsigned* flags = (unsigned*)take((size_t)BATCH * SWEEPS * sizeof(unsigned));
  (void)in_sizes; (void)n_in; (void)ws_size; (void)out_size;  // ~80.5 MB total

  hipFuncSetAttribute((const void*)combined_all_kernel,
                      hipFuncAttributeMaxDynamicSharedMemorySize, JAC_LDS_BYTES);

  zero_kernel<<<2048, 256, 0, stream>>>((double*)Theta, (size_t)BATCH * NSQ * 2);
  zero_kernel<<<2048, 256, 0, stream>>>((double*)Lamda, (size_t)BATCH * NSQ * 2);
  flags_zero_kernel<<<1, 512, 0, stream>>>(flags);
  prng_kernel<<<(KITER * BATCH * NDIM + 255) / 256, 256, 0, stream>>>(minv);

  for (int it = 0; it < KITER - 1; ++it) {
    compute_u_kernel<<<16, 256, 0, stream>>>(Theta, Lamda, rho, tau, it, u);
    assemble_kernel<<<BATCH * NSQ / 256, 256, 0, stream>>>(Theta, Lamda, u, Yre, Yim,
                                                           rho, tau, it, A32);
    combined_all_kernel<<<BATCH + 2 * BATCH, 1024, JAC_LDS_BYTES, stream>>>(
        A32, U32, prm, flags, minv, it, d1, d2);
    update_kernel<<<BATCH * 16, 256, 0, stream>>>(U32, d1, d2, rho, eta, it, Theta, Lamda);
  }
  compute_u_kernel<<<16, 256, 0, stream>>>(Theta, Lamda, rho, tau, KITER - 1, u);
  writeout_kernel<<<(OUT_ELEMS + 255) / 256, 256, 0, stream>>>(u, out);
}

// Round 9
// 14629.991 us; speedup vs baseline: 1.1239x; 1.0195x over previous
//
#include <hip/hip_runtime.h>
#include <stdint.h>

// ---------------------------------------------------------------------------
// AnmNetwork: ADMM-like complex PSD iteration. B=64, m=l=64, n=128, K=10.
//  * Sita = V relu(w + minv[rank]) V^H  (second eigh mathematically redundant)
//  * Lamda_new = (1 - eta/rho) Lamda + eta * V diag(relu(w+m)-w) V^H
//  * Output depends only on state entering iteration K-1 -> 9 eigh rounds.
//  * PRNG: JAX threefry2x32 partitionable counters (bit-exact, R5).
// R21 = REVERT to R18 (measured optimum: 1612us steady, 14.64ms total).
// R19/R20 both regressed attempting to rebalance wave0 vs rest waves --
// the straggler model is refuted: round time is set by wave0's serial
// latency chain + LDS queue, not per-wave unit counts. R18's config:
//  * Sweep fusion: ONE dispatch/iter; jacobi blocks 0..63 keep A
//    LDS-resident across all 7 sweeps; replay blocks 64..191 keep U chunks
//    LDS-resident (U=I init); params handed off via agent-scope flags.
//  * Round (ONE barrier): wave0 rotates 189 band blocks (d<=2) then
//    computes P(r+1) from its own fresh writes (same-wave LDS in-order);
//    waves 1..15 rotate 1891 rest blocks (threads 64..95 take a 3rd).
//  * A as AoS float2 (RSA=130: bank-pair (2r+c)&15, diag (3p)&15 covers all
//    16 pairs); lgkmcnt-only barriers (Pg stores drain at sweep RELEASE).
// State (Theta/Lamda), PRNG, u, writeout stay fp64. SWEEPS=7.
// ---------------------------------------------------------------------------

#define BATCH 64
#define MDIM 64
#define LDIM 64
#define NDIM 128
#define NSQ (NDIM * NDIM)
#define KITER 10
#define SWEEPS 7
#define RSA 130                                 // A row stride (float2 units)
#define JAC_LDS_BYTES (NDIM * RSA * (int)sizeof(float2))   // 133,120 B
#define RCH 12                                  // replay chunk col stride (dwords, 48B)
#define OUT_ELEMS 266240   // 64*64*64 (T) + 64*64 (uvec), f32 real parts

// ----------------------------- threefry2x32 --------------------------------
__device__ __forceinline__ void tf_block(unsigned k0, unsigned k1,
                                         unsigned& x0, unsigned& x1) {
  unsigned k2 = k0 ^ k1 ^ 0x1BD11BDAu;
  x0 += k0; x1 += k1;
#define TF_R(r) { x0 += x1; x1 = (x1 << (r)) | (x1 >> (32 - (r))); x1 ^= x0; }
  TF_R(13) TF_R(15) TF_R(26) TF_R(6)
  x0 += k1; x1 += k2 + 1u;
  TF_R(17) TF_R(29) TF_R(16) TF_R(24)
  x0 += k2; x1 += k0 + 2u;
  TF_R(13) TF_R(15) TF_R(26) TF_R(6)
  x0 += k0; x1 += k1 + 3u;
  TF_R(17) TF_R(29) TF_R(16) TF_R(24)
  x0 += k1; x1 += k2 + 4u;
  TF_R(13) TF_R(15) TF_R(26) TF_R(6)
  x0 += k2; x1 += k0 + 5u;
#undef TF_R
}

// ------------------------------- erfinv (f64) ------------------------------
__device__ double erfinv_d(double x) {
  double w = -log1p(-x * x);
  double p;
  if (w < 6.25) {
    w -= 3.125;
    const double c[23] = {
      -3.6444120640178196996e-21, -1.685059138182016589e-19,
      1.2858480715256400167e-18,  1.115787767802518096e-17,
      -1.333171662854620906e-16,  2.0972767875968561637e-17,
      6.6376381343583238325e-15,  -4.0545662729752068639e-14,
      -8.1519341976054721522e-14, 2.6335093153082322977e-12,
      -1.2975133253453532498e-11, -5.4154120542946279317e-11,
      1.051212273321532285e-09,   -4.1126339803469836976e-09,
      -2.9070369957882005086e-08, 4.2347877827932403518e-07,
      -1.3654692000834678645e-06, -1.3882523362786468719e-05,
      1.8673420803405714802e-04,  -7.4070253416626697512e-04,
      -6.0336708714301490533e-03, 2.4015818242558961693e-01,
      1.6536545626831027356e+00};
    p = c[0];
#pragma unroll
    for (int i = 1; i < 23; ++i) p = p * w + c[i];
  } else if (w < 16.0) {
    double s = sqrt(w) - 3.25;
    const double c[19] = {
      2.2137376921775787049e-09,  9.0756561938885390979e-08,
      -2.7517406297064545428e-07, 1.8239629214389227755e-08,
      1.5027403968909827627e-06,  -4.013867526981545969e-06,
      2.9234449089955446044e-06,  1.2475304481671778723e-05,
      -4.7318229009055733981e-05, 6.8284851459573175448e-05,
      2.4031110387097893999e-05,  -3.5503752036284748449e-04,
      9.5328937973738049703e-04,  -1.6882755560235047313e-03,
      2.4914420961078508066e-03,  -3.7512085075692412107e-03,
      5.3709145535900636051e-03,  1.0052589676941592334e+00,
      3.0838856104922207635e+00};
    p = c[0];
#pragma unroll
    for (int i = 1; i < 19; ++i) p = p * s + c[i];
  } else {
    double s = sqrt(w) - 5.0;
    const double c[17] = {
      -2.7109920616438573243e-11, -2.5556418169965252055e-10,
      1.5076572693500548083e-09,  -3.7894654401267369937e-09,
      7.6157012080783393804e-09,  -1.4960026627149240478e-08,
      2.9147953450901080826e-08,  -6.7711997758452339498e-08,
      2.2900482228026654717e-07,  -9.9298272942317002539e-07,
      4.5260625972231537039e-06,  -1.9681778105531670567e-05,
      7.5995277030017761139e-05,  -2.1503011930044477347e-04,
      -1.3871931833623122026e-04, 1.0103004648645343977e+00,
      4.8499064014085844221e+00};
    p = c[0];
#pragma unroll
    for (int i = 1; i < 17; ++i) p = p * s + c[i];
  }
  double z = p * x;
  const double spi2 = 0.8862269254527580;  // sqrt(pi)/2
  double ax = fabs(x);
#pragma unroll
  for (int nr = 0; nr < 2; ++nr) {
    if (ax > 0.9375) {
      double az = fabs(z);
      double corr = (erfc(az) - (1.0 - ax)) * spi2 * exp(az * az);
      az += corr;
      z = copysign(az, x);
    } else {
      z -= (erf(z) - x) * spi2 * exp(z * z);
    }
  }
  return z;
}

// ------------------------------- kernels -----------------------------------
__global__ void zero_kernel(double* p, size_t n) {
  size_t i = (size_t)blockIdx.x * blockDim.x + threadIdx.x;
  size_t stride = (size_t)gridDim.x * blockDim.x;
  for (; i < n; i += stride) p[i] = 0.0;
}

__global__ void flags_zero_kernel(unsigned* flags) {
  int tid = threadIdx.x;
  if (tid < BATCH * SWEEPS) flags[tid] = 0u;
}

__global__ void prng_kernel(double* minv) {
  int tid = blockIdx.x * blockDim.x + threadIdx.x;
  if (tid >= KITER * BATCH * NDIM) return;
  int it = tid / (BATCH * NDIM);
  int i = tid % (BATCH * NDIM);
  unsigned nk0 = 0u, nk1 = (unsigned)it;
  tf_block(0u, 42u, nk0, nk1);                       // fold_in
  unsigned c0 = 0u, c1 = (unsigned)i;                // partitionable counter
  tf_block(nk0, nk1, c0, c1);
  unsigned long long bits = ((unsigned long long)c0 << 32) | (unsigned long long)c1;
  unsigned long long fb = (bits >> 12) | 0x3FF0000000000000ull;
  double f = __builtin_bit_cast(double, fb) - 1.0;
  const double lo = __builtin_bit_cast(double, 0xBFEFFFFFFFFFFFFFull);
  double uu = f * 2.0 + lo;
  if (uu < lo) uu = lo;
  minv[tid] = 1.4142135623730951 * erfinv_d(uu);
}

__global__ void compute_u_kernel(const double2* Theta, const double2* Lamda,
                                 const float* rho, const float* tau, int it,
                                 double2* u) {
  int tid = blockIdx.x * blockDim.x + threadIdx.x;
  if (tid >= BATCH * MDIM) return;
  int b = tid / MDIM, kk = tid % MDIM;
  double r = (double)rho[it], t = (double)tau[it];
  const double2* Lb = Lamda + (size_t)b * NSQ;
  const double2* Tb = Theta + (size_t)b * NSQ;
  double ar = 0.0, ai = 0.0;
  for (int i = 0; i + kk < MDIM; ++i) {
    double2 L = Lb[i * NDIM + i + kk];
    double2 Th = Tb[i * NDIM + i + kk];
    ar += L.x + r * Th.x;
    ai += L.y + r * Th.y;
  }
  if (kk == 0) ar += -(t * 0.5) * (double)MDIM;
  double s = 1.0 / ((double)(MDIM - kk) * r);
  u[b * MDIM + kk] = make_double2(ar * s, ai * s);
}

// A32 = fp32(StackM - Lamda/r)   (U init lives in combined_all: U = I)
__global__ void assemble_kernel(const double2* Theta, const double2* Lamda,
                                const double2* u, const float* Yre, const float* Yim,
                                const float* rho, const float* tau, int it,
                                float2* A32) {
  int tid = blockIdx.x * 256 + threadIdx.x;
  if (tid >= BATCH * NSQ) return;
  int b = tid / NSQ, rem = tid % NSQ, i = rem / NDIM, j = rem % NDIM;
  double r = (double)rho[it], t = (double)tau[it];
  size_t idx = (size_t)b * NSQ + rem;
  double2 L = Lamda[idx], Th = Theta[idx];
  double axr, axi;
  if (i < MDIM && j < MDIM) {
    int d = j - i;
    double2 uv = u[b * MDIM + (d >= 0 ? d : -d)];
    double uy = (d >= 0) ? uv.y : -uv.y;
    axr = uv.x - L.x / r;
    axi = uy - L.y / r;
  } else if (i < MDIM) {
    double yr = (double)Yre[(b * MDIM + i) * LDIM + (j - MDIM)];
    double yi = (double)Yim[(b * MDIM + i) * LDIM + (j - MDIM)];
    double inv = 1.0 / (1.0 + 2.0 * r);
    axr = (yr + 2.0 * L.x + 2.0 * r * Th.x) * inv - L.x / r;
    axi = (yi + 2.0 * L.y + 2.0 * r * Th.y) * inv - L.y / r;
  } else if (j < MDIM) {
    double yr = (double)Yre[(b * MDIM + j) * LDIM + (i - MDIM)];
    double yi = -(double)Yim[(b * MDIM + j) * LDIM + (i - MDIM)];
    double inv = 1.0 / (1.0 + 2.0 * r);
    axr = (yr + 2.0 * L.x + 2.0 * r * Th.x) * inv - L.x / r;
    axi = (yi + 2.0 * L.y + 2.0 * r * Th.y) * inv - L.y / r;
  } else {
    axr = Th.x - ((i == j) ? t / (2.0 * r) : 0.0);
    axi = Th.y;
  }
  A32[idx] = make_float2((float)axr, (float)axi);
}

__device__ __forceinline__ int pair_p(int j, int r) {
  return (j == 0) ? 0 : 1 + (j - 1 + r) % 127;
}
__device__ __forceinline__ int pair_q(int j, int r) {
  return 1 + (126 - j + r) % 127;
}

// Canonical-upper accessors (AoS float2 plane, stride RSA) -> single b64 op.
__device__ __forceinline__ float2 ldc2(const float2* sA, int r, int c) {
  int rr = r <= c ? r : c, cc = r <= c ? c : r;
  float2 v = sA[rr * RSA + cc];
  if (r > c) v.y = -v.y;
  return v;
}
__device__ __forceinline__ void stc2(float2* sA, int r, int c, float zr, float zi) {
  int rr = r <= c ? r : c, cc = r <= c ? c : r;
  sA[rr * RSA + cc] = make_float2(zr, (r <= c) ? zi : -zi);
}

// Raw barrier: drain own LDS ops only -- wave0's Pg global stores stay in
// flight (drained once per sweep by the RELEASE atomic on the same wave).
__device__ __forceinline__ void bar_lgkm() {
  asm volatile("s_waitcnt lgkmcnt(0)" ::: "memory");
  __builtin_amdgcn_s_barrier();
}

// Fused dispatch: blocks 0..63 jacobi (all 7 sweeps, A LDS-resident, params
// released per sweep via device-scope flags); blocks 64..191 replay (U chunk
// LDS-resident across all 7 sweeps, init to I, acquire-spin per sweep).
__global__ __launch_bounds__(1024) void combined_all_kernel(
    const float2* __restrict__ A, float2* __restrict__ U,
    float2* __restrict__ prm,        // [SWEEPS][BATCH][127][64]
    unsigned* __restrict__ flags,    // [BATCH][SWEEPS]
    const double* __restrict__ minv, int it,
    double* __restrict__ d1, double* __restrict__ d2) {
  extern __shared__ float smem[];
  int tid = threadIdx.x;

  if (blockIdx.x >= BATCH) {
    // ------------------------- replay path --------------------------------
    if (tid >= 512) return;   // 8 working waves; no block barriers here
    int rb = blockIdx.x - BATCH;
    int wv = tid >> 6, ln = tid & 63;
    int b = rb >> 1, half = rb & 1;
    int col0 = (half * 8 + wv) * 8;
    float* cre = smem + wv * (2 * NDIM * RCH);
    float* cim = cre + NDIM * RCH;
    // U = I (chunk init in LDS; no global load)
    for (int e = ln; e < NDIM * 8; e += 64) {
      int row = e >> 3, c = e & 7;
      cre[row * RCH + c] = (row == col0 + c) ? 1.0f : 0.0f;
      cim[row * RCH + c] = 0.0f;
    }
    for (int s = 0; s < SWEEPS; ++s) {
      const float2* Pg = prm + ((size_t)s * BATCH + b) * (127 * 64);
      if (ln == 0) {   // per-wave acquire spin (waves are independent)
        while (__hip_atomic_load(&flags[b * SWEEPS + s], __ATOMIC_ACQUIRE,
                                 __HIP_MEMORY_SCOPE_AGENT) != (unsigned)(it + 1)) {
          __builtin_amdgcn_s_sleep(8);
        }
      }
      // wave64 lockstep reconvergence: all lanes proceed after ln0's acquire
      float2 prmv = Pg[ln];   // round 0 params, prefetched
      for (int r0 = 0; r0 < 127; ++r0) {
        int r = (s & 1) ? (126 - r0) : r0;
        int p = pair_p(ln, r), q = pair_q(ln, r);
        float2 nxt = prmv;
        if (r0 < 126) nxt = Pg[(r0 + 1) * 64 + ln];   // prefetch next round
        float br = prmv.x, bi = prmv.y;
        float cc = sqrtf(fmaxf(0.0f, 1.0f - br * br - bi * bi));
        float4* Rp = (float4*)(cre + p * RCH);   // 48B rows: 16B-aligned
        float4* Rq = (float4*)(cre + q * RCH);
        float4* Ip = (float4*)(cim + p * RCH);
        float4* Iq = (float4*)(cim + q * RCH);
        float4 pr0 = Rp[0], pr1 = Rp[1], pim0 = Ip[0], pim1 = Ip[1];
        float4 qr0 = Rq[0], qr1 = Rq[1], qim0 = Iq[0], qim1 = Iq[1];
#define ROTC(UPX, UPY, UQX, UQY) { float upx = UPX, upy = UPY, uqx = UQX, uqy = UQY; \
    UPX = cc * upx + (br * uqx + bi * uqy);  /* U_p <- c U_p + conj(sb) U_q */       \
    UPY = cc * upy + (br * uqy - bi * uqx);                                          \
    UQX = cc * uqx - (br * upx - bi * upy);  /* U_q <- c U_q - sb U_p */             \
    UQY = cc * uqy - (br * upy + bi * upx); }
        ROTC(pr0.x, pim0.x, qr0.x, qim0.x)
        ROTC(pr0.y, pim0.y, qr0.y, qim0.y)
        ROTC(pr0.z, pim0.z, qr0.z, qim0.z)
        ROTC(pr0.w, pim0.w, qr0.w, qim0.w)
        ROTC(pr1.x, pim1.x, qr1.x, qim1.x)
        ROTC(pr1.y, pim1.y, qr1.y, qim1.y)
        ROTC(pr1.z, pim1.z, qr1.z, qim1.z)
        ROTC(pr1.w, pim1.w, qr1.w, qim1.w)
#undef ROTC
        Rp[0] = pr0; Rp[1] = pr1; Ip[0] = pim0; Ip[1] = pim1;
        Rq[0] = qr0; Rq[1] = qr1; Iq[0] = qim0; Iq[1] = qim1;
        prmv = nxt;
        __builtin_amdgcn_wave_barrier();
      }
    }
    float2* Ug = U + (size_t)b * NSQ;
    for (int e = ln; e < NDIM * 8; e += 64) {
      int row = e >> 3, c = e & 7;
      Ug[row * NDIM + col0 + c] = make_float2(cre[row * RCH + c], cim[row * RCH + c]);
    }
    return;
  }

  // --------------------------- jacobi path --------------------------------
  // 1024 threads. Per round (ONE barrier): wave0 rotates 189 band blocks
  // (lane ln: d0 (ln,ln) + d1 (ln,ln+1)[ln<=62] + d2 (ln,ln+2)[ln<=61])
  // then computes P(r+1) (same-wave LDS in-order); waves 1..15 rotate the
  // 1891 rest blocks (2 each; threads 64..95 take a 3rd).
  float2* sA2 = (float2*)smem;    // 128 x 130 float2 (AoS re,im)
  __shared__ float4 sprm2[2][64]; // double-buffered {c, br, bi, 0}
  int b = blockIdx.x;
  const float2* Ag = A + (size_t)b * NSQ;
  for (int i = tid; i < NSQ; i += 1024) {
    sA2[(i >> 7) * RSA + (i & 127)] = Ag[i];
  }
  // rest blocks (bj-bi>=3): 1891 over threads 64..1023, indices t-64, t-64+960
  int nrest = 0;
  int rb_i[2], rb_j[2];
  rb_i[0] = rb_i[1] = 0; rb_j[0] = rb_j[1] = 0;
  if (tid >= 64) {
#pragma unroll
    for (int m = 0; m < 2; ++m) {
      int e = (tid - 64) + 960 * m;
      if (e < 1891) {
        // base(bi) = 61*bi - bi*(bi-1)/2 ; bj = bi + 3 + (e - base)
        int i = 0;
        while (i < 60 && (61 * (i + 1) - ((i + 1) * i) / 2) <= e) ++i;
        rb_i[nrest] = i;
        rb_j[nrest] = i + 3 + (e - (61 * i - (i * (i - 1)) / 2));
        ++nrest;
      }
    }
  }
  int ln = tid;   // wave0 lane = band slot base (valid when tid<64)
  __syncthreads();

  for (int s = 0; s < SWEEPS; ++s) {
    float2* Pg = prm + ((size_t)s * BATCH + b) * (127 * 64);
    const bool fwd = !(s & 1);
    const int r_init = fwd ? 0 : 126;
    auto stepP = [&](int x) {
      return fwd ? ((x == 0) ? 0 : ((x == 127) ? 1 : x + 1))
                 : ((x == 0) ? 0 : ((x == 1) ? 127 : x - 1));
    };
    auto stepQ = [&](int x) {
      return fwd ? ((x == 127) ? 1 : x + 1)
                 : ((x == 1) ? 127 : x - 1);
    };
    // wave0 trackers: rows p,q for slots ln, ln+1, ln+2
    int bp0 = pair_p(ln, r_init), bq0 = pair_q(ln, r_init);
    int bp1 = pair_p(ln + 1, r_init), bq1 = pair_q(ln + 1, r_init);
    int bp2 = pair_p(ln + 2, r_init), bq2 = pair_q(ln + 2, r_init);
    // rest trackers
    int rpi[2], rqi[2], rpj[2], rqj[2];
#pragma unroll
    for (int m = 0; m < 2; ++m) {
      rpi[m] = pair_p(rb_i[m], r_init); rqi[m] = pair_q(rb_i[m], r_init);
      rpj[m] = pair_p(rb_j[m], r_init); rqj[m] = pair_q(rb_j[m], r_init);
    }
    // param compute helper (wave0 lanes): rows (pp,qq) -> sprm2[buf] + Pg[pos]
    auto pcalc = [&](int pp, int qq, int buf, int pos) {
      float app = sA2[pp * RSA + pp].x, aqq = sA2[qq * RSA + qq].x;
      float2 g = ldc2(sA2, pp, qq);
      float ag2 = g.x * g.x + g.y * g.y;
      float cc = 1.0f, br = 0.0f, bi = 0.0f;
      if (ag2 > 1e-24f) {
        float ag = sqrtf(ag2);
        float ta = (aqq - app) / (2.0f * ag);
        float tt = -copysignf(1.0f, ta) / (fabsf(ta) + sqrtf(1.0f + ta * ta));
        cc = 1.0f / sqrtf(1.0f + tt * tt);
        float tcag = tt * cc / ag;
        br = g.x * tcag; bi = g.y * tcag;
      }
      sprm2[buf][tid] = make_float4(cc, br, bi, 0.0f);
      Pg[pos * 64 + tid] = make_float2(br, bi);   // fire-and-forget
    };
    // generic 2x2 block rotate
    auto rot = [&](int bi_s, int bj_s, int pi_, int qi_, int pj_, int qj_, int buf) {
      float2 B00 = ldc2(sA2, pi_, pj_);
      float2 B01 = ldc2(sA2, pi_, qj_);
      float2 B10 = ldc2(sA2, qi_, pj_);
      float2 B11 = ldc2(sA2, qi_, qj_);
      float4 Pi = sprm2[buf][bi_s], Pj = sprm2[buf][bj_s];
      float ci = Pi.x, bri = Pi.y, bii = Pi.z;
      float cj = Pj.x, brj = Pj.y, bij = Pj.z;
      float t00r = ci * B00.x + (bri * B10.x - bii * B10.y);
      float t00i = ci * B00.y + (bri * B10.y + bii * B10.x);
      float t01r = ci * B01.x + (bri * B11.x - bii * B11.y);
      float t01i = ci * B01.y + (bri * B11.y + bii * B11.x);
      float t10r = ci * B10.x - (bri * B00.x + bii * B00.y);
      float t10i = ci * B10.y - (bri * B00.y - bii * B00.x);
      float t11r = ci * B11.x - (bri * B01.x + bii * B01.y);
      float t11i = ci * B11.y - (bri * B01.y - bii * B01.x);
      stc2(sA2, pi_, pj_,
           cj * t00r + (brj * t01r + bij * t01i),
           cj * t00i + (brj * t01i - bij * t01r));
      stc2(sA2, pi_, qj_,
           cj * t01r - (brj * t00r - bij * t00i),
           cj * t01i - (brj * t00i + bij * t00r));
      stc2(sA2, qi_, pj_,
           cj * t10r + (brj * t11r + bij * t11i),
           cj * t10i + (brj * t11i - bij * t11r));
      stc2(sA2, qi_, qj_,
           cj * t11r - (brj * t10r - bij * t10i),
           cj * t11i - (brj * t10i + bij * t10r));
    };
    // compute half of a merged rot (inputs pre-read)
    auto rotc = [&](int bi_s, int bj_s, int pi_, int qi_, int pj_, int qj_, int buf,
                    float2 B00, float2 B01, float2 B10, float2 B11) {
      float4 Pi = sprm2[buf][bi_s], Pj = sprm2[buf][bj_s];
      float ci = Pi.x, bri = Pi.y, bii = Pi.z;
      float cj = Pj.x, brj = Pj.y, bij = Pj.z;
      float t00r = ci * B00.x + (bri * B10.x - bii * B10.y);
      float t00i = ci * B00.y + (bri * B10.y + bii * B10.x);
      float t01r = ci * B01.x + (bri * B11.x - bii * B11.y);
      float t01i = ci * B01.y + (bri * B11.y + bii * B11.x);
      float t10r = ci * B10.x - (bri * B00.x + bii * B00.y);
      float t10i = ci * B10.y - (bri * B00.y - bii * B00.x);
      float t11r = ci * B11.x - (bri * B01.x + bii * B01.y);
      float t11i = ci * B11.y - (bri * B01.y - bii * B01.x);
      stc2(sA2, pi_, pj_,
           cj * t00r + (brj * t01r + bij * t01i),
           cj * t00i + (brj * t01i - bij * t01r));
      stc2(sA2, pi_, qj_,
           cj * t01r - (brj * t00r - bij * t00i),
           cj * t01i - (brj * t00i + bij * t00r));
      stc2(sA2, qi_, pj_,
           cj * t10r + (brj * t11r + bij * t11i),
           cj * t10i + (brj * t11i - bij * t11r));
      stc2(sA2, qi_, qj_,
           cj * t11r - (brj * t10r - bij * t10i),
           cj * t11i - (brj * t10i + bij * t10r));
    };
    // ---- sweep prologue: params for seq(0) into sprm2[0]; init next-rows --
    int ppn = 0, qqn = 0;
    if (tid < 64) {
      int pp0 = pair_p(tid, r_init), qq0 = pair_q(tid, r_init);
      pcalc(pp0, qq0, 0, 0);
      ppn = stepP(pp0); qqn = stepQ(qq0);   // rows at seq(1)
    }
    bar_lgkm();
    int cur = 0;
    // ---- round loop (ONE barrier per round) ----
    for (int r0 = 0; r0 < 127; ++r0) {
      if (tid < 64) {
        rot(ln, ln, bp0, bq0, bp0, bq0, cur);
        if (ln <= 62) rot(ln, ln + 1, bp0, bq0, bp1, bq1, cur);
        if (ln <= 61) rot(ln, ln + 2, bp0, bq0, bp2, bq2, cur);
        __builtin_amdgcn_wave_barrier();   // keep compiler order: rots then P
        if (r0 < 126) {
          pcalc(ppn, qqn, cur ^ 1, r0 + 1);  // reads wave0's fresh band cells
          ppn = stepP(ppn); qqn = stepQ(qqn);
        }
      } else {
        // rest blocks: read all cells, compute, write (disjoint cells)
        float2 B00a, B01a, B10a, B11a, B00b, B01b, B10b, B11b;
        if (nrest > 0) {
          B00a = ldc2(sA2, rpi[0], rpj[0]);
          B01a = ldc2(sA2, rpi[0], rqj[0]);
          B10a = ldc2(sA2, rqi[0], rpj[0]);
          B11a = ldc2(sA2, rqi[0], rqj[0]);
        }
        if (nrest > 1) {
          B00b = ldc2(sA2, rpi[1], rpj[1]);
          B01b = ldc2(sA2, rpi[1], rqj[1]);
          B10b = ldc2(sA2, rqi[1], rpj[1]);
          B11b = ldc2(sA2, rqi[1], rqj[1]);
        }
        if (nrest > 0)
          rotc(rb_i[0], rb_j[0], rpi[0], rqi[0], rpj[0], rqj[0], cur,
               B00a, B01a, B10a, B11a);
        if (nrest > 1)
          rotc(rb_i[1], rb_j[1], rpi[1], rqi[1], rpj[1], rqj[1], cur,
               B00b, B01b, B10b, B11b);
      }
      bar_lgkm();   // all writes + sprm2[cur^1] visible for next round
      cur ^= 1;
      // step trackers to next round
      bp0 = stepP(bp0); bq0 = stepQ(bq0);
      bp1 = stepP(bp1); bq1 = stepQ(bq1);
      bp2 = stepP(bp2); bq2 = stepQ(bq2);
#pragma unroll
      for (int m = 0; m < 2; ++m) {
        rpi[m] = stepP(rpi[m]); rqi[m] = stepQ(rqi[m]);
        rpj[m] = stepP(rpj[m]); rqj[m] = stepQ(rqj[m]);
      }
    }
    // publish sweep s params: RELEASE drains wave0's outstanding Pg stores
    // (all issued by wave 0) and performs agent-scope writeback.
    if (tid == 0) {
      __hip_atomic_store(&flags[b * SWEEPS + s], (unsigned)(it + 1),
                         __ATOMIC_RELEASE, __HIP_MEMORY_SCOPE_AGENT);
    }
  }

  // fused rankd (diag is canonical); A is NOT written back (dead after this)
  if (tid < NDIM) {
    float wj = sA2[tid * RSA + tid].x;
    int rank = 0;
    for (int k2 = 0; k2 < NDIM; ++k2) {
      float wk = sA2[k2 * RSA + k2].x;
      rank += (wk < wj) || (wk == wj && k2 < tid);
    }
    double mv = minv[(it * BATCH + b) * NDIM + rank];
    double v = (double)wj + mv;
    if (v < 0.0) v = 0.0;
    d1[b * NDIM + tid] = v;
    d2[b * NDIM + tid] = v - (double)wj;
  }
}

// Theta = V diag(d1) V^H ; Lamda = (1-e/r) Lamda + e * V diag(d2) V^H.
__global__ __launch_bounds__(256) void update_kernel(
    const float2* U, const double* d1, const double* d2,
    const float* rho, const float* eta, int it,
    double2* Theta, double2* Lamda) {
  __shared__ float ViRe[32][33], ViIm[32][33];
  __shared__ float VkRe[32][33], VkIm[32][33];
  __shared__ double s1[32], s2[32];
  int blk = blockIdx.x;
  int b = blk >> 4, tile = blk & 15, ti = tile >> 2, tk = tile & 3;
  int tid = threadIdx.x;
  int lk = tid & 31, lig = tid >> 5;
  double r = (double)rho[it], e = (double)eta[it];
  double a1x[4] = {0, 0, 0, 0}, a1y[4] = {0, 0, 0, 0};
  double a2x[4] = {0, 0, 0, 0}, a2y[4] = {0, 0, 0, 0};
  const float2* Ub = U + (size_t)b * NSQ;
  for (int jc = 0; jc < 4; ++jc) {
    for (int e2 = tid; e2 < 1024; e2 += 256) {
      int rr = e2 & 31, cc2 = e2 >> 5;
      float2 v1 = Ub[(jc * 32 + cc2) * NDIM + ti * 32 + rr];
      ViRe[rr][cc2] = v1.x; ViIm[rr][cc2] = v1.y;
      float2 v2 = Ub[(jc * 32 + cc2) * NDIM + tk * 32 + rr];
      VkRe[rr][cc2] = v2.x; VkIm[rr][cc2] = v2.y;
    }
    if (tid < 32) {
      s1[tid] = d1[b * NDIM + jc * 32 + tid];
      s2[tid] = d2[b * NDIM + jc * 32 + tid];
    }
    __syncthreads();
#pragma unroll
    for (int uo = 0; uo < 4; ++uo) {
      int li = lig + uo * 8;
      double ax = a1x[uo], ay = a1y[uo], bx = a2x[uo], by = a2y[uo];
      for (int jj = 0; jj < 32; ++jj) {
        float var = ViRe[li][jj], vai = ViIm[li][jj];
        float vbr = VkRe[lk][jj], vbi = VkIm[lk][jj];
        double pr = (double)(var * vbr + vai * vbi);
        double pi = (double)(vai * vbr - var * vbi);
        ax += s1[jj] * pr; ay += s1[jj] * pi;
        bx += s2[jj] * pr; by += s2[jj] * pi;
      }
      a1x[uo] = ax; a1y[uo] = ay; a2x[uo] = bx; a2y[uo] = by;
    }
    __syncthreads();
  }
  double lf = 1.0 - e / r;
#pragma unroll
  for (int uo = 0; uo < 4; ++uo) {
    int gi = ti * 32 + lig + uo * 8, gk = tk * 32 + lk;
    size_t idx = (size_t)b * NSQ + gi * NDIM + gk;
    Theta[idx] = make_double2(a1x[uo], a1y[uo]);
    double2 Lold = Lamda[idx];
    Lamda[idx] = make_double2(lf * Lold.x + e * a2x[uo], lf * Lold.y + e * a2y[uo]);
  }
}

// OUTPUT (float32 real parts): T[i][j] = u[|i-j|].re ; uvec.re = u.re
__global__ void writeout_kernel(const double2* u, float* out) {
  int tid = blockIdx.x * 256 + threadIdx.x;
  if (tid >= OUT_ELEMS) return;
  double re;
  if (tid < BATCH * MDIM * MDIM) {
    int b = tid >> 12, rem = tid & 4095, i = rem >> 6, j = rem & 63;
    int d = j - i;
    re = u[b * MDIM + (d >= 0 ? d : -d)].x;
  } else {
    int k2 = tid - BATCH * MDIM * MDIM;
    int b = k2 >> 6, kk = k2 & 63;
    re = u[b * MDIM + kk].x;
  }
  out[tid] = (float)re;
}

// ------------------------------- launch ------------------------------------
extern "C" void kernel_launch(void* const* d_in, const int* in_sizes, int n_in,
                              void* d_out, int out_size, void* d_ws, size_t ws_size,
                              hipStream_t stream) {
  const float* Yre = (const float*)d_in[0];
  const float* Yim = (const float*)d_in[1];
  const float* rho = (const float*)d_in[2];
  const float* tau = (const float*)d_in[3];
  const float* eta = (const float*)d_in[4];
  float* out = (float*)d_out;

  char* ws = (char*)d_ws;
  size_t off = 0;
  auto take = [&](size_t bytes) -> char* {
    char* p = ws + off;
    off += (bytes + 255) & ~(size_t)255;
    return p;
  };
  double2* u     = (double2*)take((size_t)BATCH * MDIM * sizeof(double2));
  double*  minv  = (double*)take((size_t)KITER * BATCH * NDIM * sizeof(double));
  double*  d1    = (double*)take((size_t)BATCH * NDIM * sizeof(double));
  double*  d2    = (double*)take((size_t)BATCH * NDIM * sizeof(double));
  double2* Lamda = (double2*)take((size_t)BATCH * NSQ * sizeof(double2));  // 16.8 MB
  double2* Theta = (double2*)take((size_t)BATCH * NSQ * sizeof(double2));  // 16.8 MB
  float2*  A32   = (float2*)take((size_t)BATCH * NSQ * sizeof(float2));    //  8.4 MB
  float2*  U32   = (float2*)take((size_t)BATCH * NSQ * sizeof(float2));    //  8.4 MB
  float2*  prm   = (float2*)take((size_t)SWEEPS * BATCH * 127 * 64 * sizeof(float2)); // 29.4 MB
  unsigned* flags = (unsigned*)take((size_t)BATCH * SWEEPS * sizeof(unsigned));
  (void)in_sizes; (void)n_in; (void)ws_size; (void)out_size;  // ~80.5 MB total

  hipFuncSetAttribute((const void*)combined_all_kernel,
                      hipFuncAttributeMaxDynamicSharedMemorySize, JAC_LDS_BYTES);

  zero_kernel<<<2048, 256, 0, stream>>>((double*)Theta, (size_t)BATCH * NSQ * 2);
  zero_kernel<<<2048, 256, 0, stream>>>((double*)Lamda, (size_t)BATCH * NSQ * 2);
  flags_zero_kernel<<<1, 512, 0, stream>>>(flags);
  prng_kernel<<<(KITER * BATCH * NDIM + 255) / 256, 256, 0, stream>>>(minv);

  for (int it = 0; it < KITER - 1; ++it) {
    compute_u_kernel<<<16, 256, 0, stream>>>(Theta, Lamda, rho, tau, it, u);
    assemble_kernel<<<BATCH * NSQ / 256, 256, 0, stream>>>(Theta, Lamda, u, Yre, Yim,
                                                           rho, tau, it, A32);
    combined_all_kernel<<<BATCH + 2 * BATCH, 1024, JAC_LDS_BYTES, stream>>>(
        A32, U32, prm, flags, minv, it, d1, d2);
    update_kernel<<<BATCH * 16, 256, 0, stream>>>(U32, d1, d2, rho, eta, it, Theta, Lamda);
  }
  compute_u_kernel<<<16, 256, 0, stream>>>(Theta, Lamda, rho, tau, KITER - 1, u);
  writeout_kernel<<<(OUT_ELEMS + 255) / 256, 256, 0, stream>>>(u, out);
}